// Round 1
// baseline (301.018 us; speedup 1.0000x reference)
//
#include <hip/hip_runtime.h>
#include <math.h>

#define N 6144
#define ATTR 512
#define HID 256
#define EMB 16
#define ALPHA 0.2f
#define MAXDEG 192

// ---------------------------------------------------------------------------
// K1: h1 = x @ W1   [6144,512] @ [512,256] fp32, LDS-tiled 64x64, K-tile 32
// ---------------------------------------------------------------------------
__global__ __launch_bounds__(256) void k_gemm1(const float* __restrict__ x,
                                               const float* __restrict__ W1,
                                               float* __restrict__ h1) {
  __shared__ float As[64][33];
  __shared__ float Bs[32][65];
  const int bx = blockIdx.x & 3;   // 256/64 = 4 col tiles
  const int by = blockIdx.x >> 2;  // 6144/64 = 96 row tiles
  const int tid = threadIdx.x;
  const int tx = tid & 15, ty = tid >> 4;
  const int row0 = by * 64, col0 = bx * 64;
  float acc[4][4] = {};
  for (int kt = 0; kt < ATTR; kt += 32) {
    for (int l = tid; l < 64 * 32; l += 256) {
      int r = l >> 5, c = l & 31;
      As[r][c] = x[(size_t)(row0 + r) * ATTR + kt + c];
    }
    for (int l = tid; l < 32 * 64; l += 256) {
      int r = l >> 6, c = l & 63;
      Bs[r][c] = W1[(size_t)(kt + r) * HID + col0 + c];
    }
    __syncthreads();
#pragma unroll 8
    for (int k = 0; k < 32; ++k) {
      float a[4], b[4];
#pragma unroll
      for (int i = 0; i < 4; ++i) { a[i] = As[ty * 4 + i][k]; }
#pragma unroll
      for (int j = 0; j < 4; ++j) { b[j] = Bs[k][tx * 4 + j]; }
#pragma unroll
      for (int i = 0; i < 4; ++i) {
#pragma unroll
        for (int j = 0; j < 4; ++j) { acc[i][j] += a[i] * b[j]; }
      }
    }
    __syncthreads();
  }
#pragma unroll
  for (int i = 0; i < 4; ++i) {
#pragma unroll
    for (int j = 0; j < 4; ++j) {
      h1[(size_t)(row0 + ty * 4 + i) * HID + col0 + tx * 4 + j] = acc[i][j];
    }
  }
}

// ---------------------------------------------------------------------------
// K2: f1s[i] = h1[i,:]·a_self1 ; f1n[i] = h1[i,:]·a_neigh1   (one wave/row)
// ---------------------------------------------------------------------------
__global__ __launch_bounds__(256) void k_f1(const float* __restrict__ h1,
                                            const float* __restrict__ a_s,
                                            const float* __restrict__ a_n,
                                            float* __restrict__ f1s,
                                            float* __restrict__ f1n) {
  const int wid = (blockIdx.x * 256 + threadIdx.x) >> 6;
  const int lane = threadIdx.x & 63;
  const float* hrow = h1 + (size_t)wid * HID;
  float ss = 0.0f, sn = 0.0f;
#pragma unroll
  for (int c0 = 0; c0 < HID; c0 += 64) {
    float h = hrow[c0 + lane];
    ss += h * a_s[c0 + lane];
    sn += h * a_n[c0 + lane];
  }
#pragma unroll
  for (int off = 32; off; off >>= 1) {
    ss += __shfl_xor(ss, off);
    sn += __shfl_xor(sn, off);
  }
  if (lane == 0) { f1s[wid] = ss; f1n[wid] = sn; }
}

// ---------------------------------------------------------------------------
// K3: sparse structure extraction: per row ordered neighbor list + M gather
//     (one wave per row, ballot/popc compaction — deterministic & ordered)
// ---------------------------------------------------------------------------
__global__ __launch_bounds__(256) void k_extract(const float* __restrict__ adj,
                                                 const float* __restrict__ Mm,
                                                 int* __restrict__ nbr,
                                                 float* __restrict__ mval,
                                                 int* __restrict__ deg) {
  const int wid = (blockIdx.x * 256 + threadIdx.x) >> 6;
  const int lane = threadIdx.x & 63;
  const float* arow = adj + (size_t)wid * N;
  const float* mrow = Mm + (size_t)wid * N;
  int* nrow = nbr + (size_t)wid * MAXDEG;
  float* mout = mval + (size_t)wid * MAXDEG;
  int count = 0;
  for (int base = 0; base < N; base += 64) {
    float a = arow[base + lane];
    bool hit = (a > 0.0f);
    unsigned long long mask = __ballot(hit);
    if (hit) {
      int pos = count + __popcll(mask & ((1ull << lane) - 1ull));
      if (pos < MAXDEG) {
        nrow[pos] = base + lane;
        mout[pos] = mrow[base + lane];
      }
    }
    count += __popcll(mask);
  }
  if (lane == 0) deg[wid] = count > MAXDEG ? MAXDEG : count;
}

// ---------------------------------------------------------------------------
// K4: sparse attention layer 1: out1[i,:] = elu( sum_j attn_ij * h1[j,:] )
//     one block (256 thr) per row; wave 0 does softmax, all threads gather
// ---------------------------------------------------------------------------
__global__ __launch_bounds__(256) void k_attn1(const float* __restrict__ h1,
                                               const float* __restrict__ f1s,
                                               const float* __restrict__ f1n,
                                               const int* __restrict__ nbr,
                                               const float* __restrict__ mval,
                                               const int* __restrict__ deg,
                                               float* __restrict__ out1) {
  __shared__ float p[MAXDEG];
  __shared__ int nb[MAXDEG];
  const int i = blockIdx.x;
  const int tid = threadIdx.x;
  const int d = deg[i];
  if (d > 0 && tid < 64) {
    const float fsi = f1s[i];
    float lmax = -3.0e38f;
    for (int j = tid; j < d; j += 64) {
      int nj = nbr[(size_t)i * MAXDEG + j];
      nb[j] = nj;
      float v = (fsi + f1n[nj]) * mval[(size_t)i * MAXDEG + j];
      float e = v > 0.0f ? v : ALPHA * v;
      p[j] = e;
      lmax = fmaxf(lmax, e);
    }
#pragma unroll
    for (int off = 32; off; off >>= 1) lmax = fmaxf(lmax, __shfl_xor(lmax, off));
    float lsum = 0.0f;
    for (int j = tid; j < d; j += 64) {
      float t = expf(p[j] - lmax);
      p[j] = t;
      lsum += t;
    }
#pragma unroll
    for (int off = 32; off; off >>= 1) lsum += __shfl_xor(lsum, off);
    float inv = 1.0f / lsum;
    for (int j = tid; j < d; j += 64) p[j] *= inv;
  }
  __syncthreads();
  float acc = 0.0f;
  if (d > 0) {
    for (int j = 0; j < d; ++j) {
      acc += p[j] * h1[(size_t)nb[j] * HID + tid];
    }
  } else {
    // reference: all-masked row -> uniform softmax over all N
    for (int j = 0; j < N; ++j) acc += h1[(size_t)j * HID + tid];
    acc *= (1.0f / (float)N);
  }
  out1[(size_t)i * HID + tid] = acc > 0.0f ? acc : expm1f(acc);
}

// ---------------------------------------------------------------------------
// K5: h2 = out1 @ W2 ([6144,256]@[256,16]) + f2s/f2n epilogue
// ---------------------------------------------------------------------------
__global__ __launch_bounds__(256) void k_gemm2(const float* __restrict__ out1,
                                               const float* __restrict__ W2,
                                               const float* __restrict__ a_s,
                                               const float* __restrict__ a_n,
                                               float* __restrict__ h2,
                                               float* __restrict__ f2s,
                                               float* __restrict__ f2n) {
  __shared__ float Hs[16][HID + 1];
  __shared__ float Ws[HID][EMB + 1];
  const int row0 = blockIdx.x * 16;
  const int tid = threadIdx.x;
  for (int l = tid; l < 16 * HID; l += 256) {
    Hs[l >> 8][l & 255] = out1[(size_t)(row0 + (l >> 8)) * HID + (l & 255)];
  }
  for (int l = tid; l < HID * EMB; l += 256) {
    Ws[l >> 4][l & 15] = W2[l];
  }
  __syncthreads();
  const int r = tid >> 4, c = tid & 15;
  float acc = 0.0f;
  for (int k = 0; k < HID; ++k) acc += Hs[r][k] * Ws[k][c];
  h2[(size_t)(row0 + r) * EMB + c] = acc;
  float vs = acc * a_s[c], vn = acc * a_n[c];
#pragma unroll
  for (int off = 1; off < 16; off <<= 1) {
    vs += __shfl_xor(vs, off);
    vn += __shfl_xor(vn, off);
  }
  if (c == 0) { f2s[row0 + r] = vs; f2n[row0 + r] = vn; }
}

// ---------------------------------------------------------------------------
// K6: sparse attention layer 2 + elu + L2-normalize -> z  (one wave per row)
// ---------------------------------------------------------------------------
__global__ __launch_bounds__(256) void k_attn2(const float* __restrict__ h2,
                                               const float* __restrict__ f2s,
                                               const float* __restrict__ f2n,
                                               const int* __restrict__ nbr,
                                               const float* __restrict__ mval,
                                               const int* __restrict__ deg,
                                               float* __restrict__ z) {
  __shared__ float p[4][MAXDEG];
  __shared__ int nb[4][MAXDEG];
  const int w = threadIdx.x >> 6, lane = threadIdx.x & 63;
  const int i = blockIdx.x * 4 + w;
  const int d = deg[i];
  if (d > 0) {
    const float fsi = f2s[i];
    float lmax = -3.0e38f;
    for (int j = lane; j < d; j += 64) {
      int nj = nbr[(size_t)i * MAXDEG + j];
      nb[w][j] = nj;
      float v = (fsi + f2n[nj]) * mval[(size_t)i * MAXDEG + j];
      float e = v > 0.0f ? v : ALPHA * v;
      p[w][j] = e;
      lmax = fmaxf(lmax, e);
    }
#pragma unroll
    for (int off = 32; off; off >>= 1) lmax = fmaxf(lmax, __shfl_xor(lmax, off));
    float lsum = 0.0f;
    for (int j = lane; j < d; j += 64) {
      float t = expf(p[w][j] - lmax);
      p[w][j] = t;
      lsum += t;
    }
#pragma unroll
    for (int off = 32; off; off >>= 1) lsum += __shfl_xor(lsum, off);
    float inv = 1.0f / lsum;
    for (int j = lane; j < d; j += 64) p[w][j] *= inv;
  }
  __syncthreads();
  const int g = lane >> 4, c = lane & 15;
  float acc = 0.0f;
  if (d > 0) {
    for (int j = g; j < d; j += 4) {
      acc += p[w][j] * h2[(size_t)nb[w][j] * EMB + c];
    }
  } else {
    for (int j = g; j < N; j += 4) acc += h2[(size_t)j * EMB + c];
  }
  acc += __shfl_xor(acc, 16);
  acc += __shfl_xor(acc, 32);
  if (d == 0) acc *= (1.0f / (float)N);
  float val = acc > 0.0f ? acc : expm1f(acc);
  float sq = val * val;
#pragma unroll
  for (int off = 1; off < 16; off <<= 1) sq += __shfl_xor(sq, off);
  float nrm = fmaxf(sqrtf(sq), 1e-12f);
  float zv = val / nrm;
  if (lane < 16) z[(size_t)i * EMB + lane] = zv;
}

// ---------------------------------------------------------------------------
// K7: A[i,j] = sigmoid(s - 1/s), s = z_i · z_j.  8 rows x 1024 cols per block
// ---------------------------------------------------------------------------
__device__ __forceinline__ float sig_of(float s) {
  float t = s - 1.0f / s;
  return 1.0f / (1.0f + expf(-t));
}

__global__ __launch_bounds__(256) void k_apred(const float* __restrict__ z,
                                               float* __restrict__ A) {
  __shared__ float zi_s[8 * EMB];
  const int i0 = blockIdx.y * 8;
  const int tid = threadIdx.x;
  if (tid < 8 * EMB) zi_s[tid] = z[(size_t)i0 * EMB + tid];
  const int j0 = blockIdx.x * 1024 + tid * 4;
  float zj[4][EMB];
  const float4* zp = (const float4*)(z + (size_t)j0 * EMB);
#pragma unroll
  for (int q = 0; q < 4; ++q) {
#pragma unroll
    for (int kk = 0; kk < 4; ++kk) {
      float4 v = zp[q * 4 + kk];
      zj[q][kk * 4 + 0] = v.x;
      zj[q][kk * 4 + 1] = v.y;
      zj[q][kk * 4 + 2] = v.z;
      zj[q][kk * 4 + 3] = v.w;
    }
  }
  __syncthreads();
  for (int ii = 0; ii < 8; ++ii) {
    float acc0 = 0.0f, acc1 = 0.0f, acc2 = 0.0f, acc3 = 0.0f;
#pragma unroll
    for (int k = 0; k < EMB; ++k) {
      float a = zi_s[ii * EMB + k];
      acc0 += a * zj[0][k];
      acc1 += a * zj[1][k];
      acc2 += a * zj[2][k];
      acc3 += a * zj[3][k];
    }
    float4 o;
    o.x = sig_of(acc0);
    o.y = sig_of(acc1);
    o.z = sig_of(acc2);
    o.w = sig_of(acc3);
    *(float4*)(A + (size_t)(i0 + ii) * N + j0) = o;
  }
}

// ---------------------------------------------------------------------------
extern "C" void kernel_launch(void* const* d_in, const int* in_sizes, int n_in,
                              void* d_out, int out_size, void* d_ws, size_t ws_size,
                              hipStream_t stream) {
  const float* x   = (const float*)d_in[0];
  const float* adj = (const float*)d_in[1];
  const float* Mm  = (const float*)d_in[2];
  const float* W1  = (const float*)d_in[3];
  const float* a1s = (const float*)d_in[4];
  const float* a1n = (const float*)d_in[5];
  const float* W2  = (const float*)d_in[6];
  const float* a2s = (const float*)d_in[7];
  const float* a2n = (const float*)d_in[8];

  // Scratch carved from the A_pred region of d_out (fully overwritten by k_apred,
  // which reads only z).  ~5.7M floats used of the 37.7M available.
  float* out = (float*)d_out;
  float* h1   = out;                          // N*HID
  float* out1 = h1 + (size_t)N * HID;         // N*HID
  float* h2   = out1 + (size_t)N * HID;       // N*EMB
  float* f1s  = h2 + (size_t)N * EMB;         // N
  float* f1n  = f1s + N;                      // N
  float* f2s  = f1n + N;                      // N
  float* f2n  = f2s + N;                      // N
  float* mval = f2n + N;                      // N*MAXDEG
  int*   nbr  = (int*)(mval + (size_t)N * MAXDEG);  // N*MAXDEG
  int*   deg  = nbr + (size_t)N * MAXDEG;           // N
  float* z    = out + (size_t)N * N;          // real output (second tuple elem)
  float* A    = out;                          // real output (first tuple elem)

  hipLaunchKernelGGL(k_extract, dim3(N / 4), dim3(256), 0, stream, adj, Mm, nbr, mval, deg);
  hipLaunchKernelGGL(k_gemm1, dim3((N / 64) * (HID / 64)), dim3(256), 0, stream, x, W1, h1);
  hipLaunchKernelGGL(k_f1, dim3(N / 4), dim3(256), 0, stream, h1, a1s, a1n, f1s, f1n);
  hipLaunchKernelGGL(k_attn1, dim3(N), dim3(256), 0, stream, h1, f1s, f1n, nbr, mval, deg, out1);
  hipLaunchKernelGGL(k_gemm2, dim3(N / 16), dim3(256), 0, stream, out1, W2, a2s, a2n, h2, f2s, f2n);
  hipLaunchKernelGGL(k_attn2, dim3(N / 4), dim3(256), 0, stream, h2, f2s, f2n, nbr, mval, deg, z);
  hipLaunchKernelGGL(k_apred, dim3(N / 1024, N / 8), dim3(256), 0, stream, z, A);
}

// Round 4
// 238.307 us; speedup vs baseline: 1.2632x; 1.2632x over previous
//
#include <hip/hip_runtime.h>
#include <math.h>

#define N 6144
#define ATTR 512
#define HID 256
#define EMB 16
#define ALPHA 0.2f
#define MAXDEG 192
#define BM 32
#define BN 64
#define BK 32

// ---------------------------------------------------------------------------
// K1: h1 = x @ W1  [6144,512]@[512,256] fp32.  Tile 32x64, 768 blocks (3/CU).
// Per-output accumulation is BIT-IDENTICAL to the round-1 kernel (sequential
// k = 0..511, single fmac chain) — only the tiling/LDS layout changed.
// ---------------------------------------------------------------------------
__global__ __launch_bounds__(256) void k_gemm1(const float* __restrict__ x,
                                               const float* __restrict__ W1,
                                               float* __restrict__ h1) {
  __shared__ float AsT[BK][BM + 2];  // [k][row], LD=34 (even -> float2 aligned)
  __shared__ float Bs[BK][BN + 4];   // [k][col], LD=68 (mult of 4 -> float4)
  const int ct = blockIdx.x & 3;   // HID/64 = 4 col tiles
  const int rt = blockIdx.x >> 2;  // N/32 = 192 row tiles
  const int tid = threadIdx.x;
  const int tx = tid & 15;         // col quad
  const int tyr = tid >> 4;        // row pair
  const int row0 = rt * BM, col0 = ct * BN;
  float acc[2][4] = {};
  for (int kt = 0; kt < ATTR; kt += BK) {
    {
      const int r = tid >> 3;      // 0..31
      const int kq = tid & 7;      // 0..7
      float4 v = *(const float4*)&x[(size_t)(row0 + r) * ATTR + kt + kq * 4];
      AsT[kq * 4 + 0][r] = v.x;
      AsT[kq * 4 + 1][r] = v.y;
      AsT[kq * 4 + 2][r] = v.z;
      AsT[kq * 4 + 3][r] = v.w;
    }
#pragma unroll
    for (int l = tid; l < 512; l += 256) {
      const int r = l >> 4;        // k 0..31
      const int cq = l & 15;       // col quad
      *(float4*)&Bs[r][cq * 4] =
          *(const float4*)&W1[(size_t)(kt + r) * HID + col0 + cq * 4];
    }
    __syncthreads();
#pragma unroll 8
    for (int k = 0; k < BK; ++k) {
      const float2 a = *(const float2*)&AsT[k][tyr * 2];
      const float4 b = *(const float4*)&Bs[k][tx * 4];
      acc[0][0] += a.x * b.x; acc[0][1] += a.x * b.y;
      acc[0][2] += a.x * b.z; acc[0][3] += a.x * b.w;
      acc[1][0] += a.y * b.x; acc[1][1] += a.y * b.y;
      acc[1][2] += a.y * b.z; acc[1][3] += a.y * b.w;
    }
    __syncthreads();
  }
#pragma unroll
  for (int i = 0; i < 2; ++i) {
    float4 o = {acc[i][0], acc[i][1], acc[i][2], acc[i][3]};
    *(float4*)&h1[(size_t)(row0 + tyr * 2 + i) * HID + col0 + tx * 4] = o;
  }
}

// ---------------------------------------------------------------------------
// K2: f1s[i] = h1[i,:]·a_self1 ; f1n[i] = h1[i,:]·a_neigh1   (one wave/row)
// ---------------------------------------------------------------------------
__global__ __launch_bounds__(256) void k_f1(const float* __restrict__ h1,
                                            const float* __restrict__ a_s,
                                            const float* __restrict__ a_n,
                                            float* __restrict__ f1s,
                                            float* __restrict__ f1n) {
  const int wid = (blockIdx.x * 256 + threadIdx.x) >> 6;
  const int lane = threadIdx.x & 63;
  const float* hrow = h1 + (size_t)wid * HID;
  float ss = 0.0f, sn = 0.0f;
#pragma unroll
  for (int c0 = 0; c0 < HID; c0 += 64) {
    float h = hrow[c0 + lane];
    ss += h * a_s[c0 + lane];
    sn += h * a_n[c0 + lane];
  }
#pragma unroll
  for (int off = 32; off; off >>= 1) {
    ss += __shfl_xor(ss, off);
    sn += __shfl_xor(sn, off);
  }
  if (lane == 0) { f1s[wid] = ss; f1n[wid] = sn; }
}

// ---------------------------------------------------------------------------
// K3: sparse structure extraction: per row ordered neighbor list + M gather
//     (one wave per row, ballot/popc compaction — round-1 known-good version)
// ---------------------------------------------------------------------------
__global__ __launch_bounds__(256) void k_extract(const float* __restrict__ adj,
                                                 const float* __restrict__ Mm,
                                                 int* __restrict__ nbr,
                                                 float* __restrict__ mval,
                                                 int* __restrict__ deg) {
  const int wid = (blockIdx.x * 256 + threadIdx.x) >> 6;
  const int lane = threadIdx.x & 63;
  const float* arow = adj + (size_t)wid * N;
  const float* mrow = Mm + (size_t)wid * N;
  int* nrow = nbr + (size_t)wid * MAXDEG;
  float* mout = mval + (size_t)wid * MAXDEG;
  int count = 0;
  for (int base = 0; base < N; base += 64) {
    float a = arow[base + lane];
    bool hit = (a > 0.0f);
    unsigned long long mask = __ballot(hit);
    if (hit) {
      int pos = count + __popcll(mask & ((1ull << lane) - 1ull));
      if (pos < MAXDEG) {
        nrow[pos] = base + lane;
        mout[pos] = mrow[base + lane];
      }
    }
    count += __popcll(mask);
  }
  if (lane == 0) deg[wid] = count > MAXDEG ? MAXDEG : count;
}

// ---------------------------------------------------------------------------
// K4: sparse attention layer 1: out1[i,:] = elu( sum_j attn_ij * h1[j,:] )
// ---------------------------------------------------------------------------
__global__ __launch_bounds__(256) void k_attn1(const float* __restrict__ h1,
                                               const float* __restrict__ f1s,
                                               const float* __restrict__ f1n,
                                               const int* __restrict__ nbr,
                                               const float* __restrict__ mval,
                                               const int* __restrict__ deg,
                                               float* __restrict__ out1) {
  __shared__ float p[MAXDEG];
  __shared__ int nb[MAXDEG];
  const int i = blockIdx.x;
  const int tid = threadIdx.x;
  const int d = deg[i];
  if (d > 0 && tid < 64) {
    const float fsi = f1s[i];
    float lmax = -3.0e38f;
    for (int j = tid; j < d; j += 64) {
      int nj = nbr[(size_t)i * MAXDEG + j];
      nb[j] = nj;
      float v = (fsi + f1n[nj]) * mval[(size_t)i * MAXDEG + j];
      float e = v > 0.0f ? v : ALPHA * v;
      p[j] = e;
      lmax = fmaxf(lmax, e);
    }
#pragma unroll
    for (int off = 32; off; off >>= 1) lmax = fmaxf(lmax, __shfl_xor(lmax, off));
    float lsum = 0.0f;
    for (int j = tid; j < d; j += 64) {
      float t = expf(p[j] - lmax);
      p[j] = t;
      lsum += t;
    }
#pragma unroll
    for (int off = 32; off; off >>= 1) lsum += __shfl_xor(lsum, off);
    float inv = 1.0f / lsum;
    for (int j = tid; j < d; j += 64) p[j] *= inv;
  }
  __syncthreads();
  float acc = 0.0f;
  if (d > 0) {
    for (int j = 0; j < d; ++j) {
      acc += p[j] * h1[(size_t)nb[j] * HID + tid];
    }
  } else {
    for (int j = 0; j < N; ++j) acc += h1[(size_t)j * HID + tid];
    acc *= (1.0f / (float)N);
  }
  out1[(size_t)i * HID + tid] = acc > 0.0f ? acc : expm1f(acc);
}

// ---------------------------------------------------------------------------
// K5: h2 = out1 @ W2 ([6144,256]@[256,16]) + f2s/f2n epilogue
// ---------------------------------------------------------------------------
__global__ __launch_bounds__(256) void k_gemm2(const float* __restrict__ out1,
                                               const float* __restrict__ W2,
                                               const float* __restrict__ a_s,
                                               const float* __restrict__ a_n,
                                               float* __restrict__ h2,
                                               float* __restrict__ f2s,
                                               float* __restrict__ f2n) {
  __shared__ float Hs[16][HID + 1];
  __shared__ float Ws[HID][EMB + 1];
  const int row0 = blockIdx.x * 16;
  const int tid = threadIdx.x;
  for (int l = tid; l < 16 * HID; l += 256) {
    Hs[l >> 8][l & 255] = out1[(size_t)(row0 + (l >> 8)) * HID + (l & 255)];
  }
  for (int l = tid; l < HID * EMB; l += 256) {
    Ws[l >> 4][l & 15] = W2[l];
  }
  __syncthreads();
  const int r = tid >> 4, c = tid & 15;
  float acc = 0.0f;
  for (int k = 0; k < HID; ++k) acc += Hs[r][k] * Ws[k][c];
  h2[(size_t)(row0 + r) * EMB + c] = acc;
  float vs = acc * a_s[c], vn = acc * a_n[c];
#pragma unroll
  for (int off = 1; off < 16; off <<= 1) {
    vs += __shfl_xor(vs, off);
    vn += __shfl_xor(vn, off);
  }
  if (c == 0) { f2s[row0 + r] = vs; f2n[row0 + r] = vn; }
}

// ---------------------------------------------------------------------------
// K6: sparse attention layer 2 + elu + L2-normalize -> z  (one wave per row)
// ---------------------------------------------------------------------------
__global__ __launch_bounds__(256) void k_attn2(const float* __restrict__ h2,
                                               const float* __restrict__ f2s,
                                               const float* __restrict__ f2n,
                                               const int* __restrict__ nbr,
                                               const float* __restrict__ mval,
                                               const int* __restrict__ deg,
                                               float* __restrict__ z) {
  __shared__ float p[4][MAXDEG];
  __shared__ int nb[4][MAXDEG];
  const int w = threadIdx.x >> 6, lane = threadIdx.x & 63;
  const int i = blockIdx.x * 4 + w;
  const int d = deg[i];
  if (d > 0) {
    const float fsi = f2s[i];
    float lmax = -3.0e38f;
    for (int j = lane; j < d; j += 64) {
      int nj = nbr[(size_t)i * MAXDEG + j];
      nb[w][j] = nj;
      float v = (fsi + f2n[nj]) * mval[(size_t)i * MAXDEG + j];
      float e = v > 0.0f ? v : ALPHA * v;
      p[w][j] = e;
      lmax = fmaxf(lmax, e);
    }
#pragma unroll
    for (int off = 32; off; off >>= 1) lmax = fmaxf(lmax, __shfl_xor(lmax, off));
    float lsum = 0.0f;
    for (int j = lane; j < d; j += 64) {
      float t = expf(p[w][j] - lmax);
      p[w][j] = t;
      lsum += t;
    }
#pragma unroll
    for (int off = 32; off; off >>= 1) lsum += __shfl_xor(lsum, off);
    float inv = 1.0f / lsum;
    for (int j = lane; j < d; j += 64) p[w][j] *= inv;
  }
  __syncthreads();
  const int g = lane >> 4, c = lane & 15;
  float acc = 0.0f;
  if (d > 0) {
    for (int j = g; j < d; j += 4) {
      acc += p[w][j] * h2[(size_t)nb[w][j] * EMB + c];
    }
  } else {
    for (int j = g; j < N; j += 4) acc += h2[(size_t)j * EMB + c];
  }
  acc += __shfl_xor(acc, 16);
  acc += __shfl_xor(acc, 32);
  if (d == 0) acc *= (1.0f / (float)N);
  float val = acc > 0.0f ? acc : expm1f(acc);
  float sq = val * val;
#pragma unroll
  for (int off = 1; off < 16; off <<= 1) sq += __shfl_xor(sq, off);
  float nrm = fmaxf(sqrtf(sq), 1e-12f);
  float zv = val / nrm;
  if (lane < 16) z[(size_t)i * EMB + lane] = zv;
}

// ---------------------------------------------------------------------------
// K7: A[i,j] = sigmoid(s - 1/s), s = z_i · z_j.  8 rows x 1024 cols per block
// ---------------------------------------------------------------------------
__device__ __forceinline__ float sig_of(float s) {
  float t = s - 1.0f / s;
  return 1.0f / (1.0f + expf(-t));
}

__global__ __launch_bounds__(256) void k_apred(const float* __restrict__ z,
                                               float* __restrict__ A) {
  __shared__ float zi_s[8 * EMB];
  const int i0 = blockIdx.y * 8;
  const int tid = threadIdx.x;
  if (tid < 8 * EMB) zi_s[tid] = z[(size_t)i0 * EMB + tid];
  const int j0 = blockIdx.x * 1024 + tid * 4;
  float zj[4][EMB];
  const float4* zp = (const float4*)(z + (size_t)j0 * EMB);
#pragma unroll
  for (int q = 0; q < 4; ++q) {
#pragma unroll
    for (int kk = 0; kk < 4; ++kk) {
      float4 v = zp[q * 4 + kk];
      zj[q][kk * 4 + 0] = v.x;
      zj[q][kk * 4 + 1] = v.y;
      zj[q][kk * 4 + 2] = v.z;
      zj[q][kk * 4 + 3] = v.w;
    }
  }
  __syncthreads();
  for (int ii = 0; ii < 8; ++ii) {
    float acc0 = 0.0f, acc1 = 0.0f, acc2 = 0.0f, acc3 = 0.0f;
#pragma unroll
    for (int k = 0; k < EMB; ++k) {
      float a = zi_s[ii * EMB + k];
      acc0 += a * zj[0][k];
      acc1 += a * zj[1][k];
      acc2 += a * zj[2][k];
      acc3 += a * zj[3][k];
    }
    float4 o;
    o.x = sig_of(acc0);
    o.y = sig_of(acc1);
    o.z = sig_of(acc2);
    o.w = sig_of(acc3);
    *(float4*)(A + (size_t)(i0 + ii) * N + j0) = o;
  }
}

// ---------------------------------------------------------------------------
extern "C" void kernel_launch(void* const* d_in, const int* in_sizes, int n_in,
                              void* d_out, int out_size, void* d_ws, size_t ws_size,
                              hipStream_t stream) {
  const float* x   = (const float*)d_in[0];
  const float* adj = (const float*)d_in[1];
  const float* Mm  = (const float*)d_in[2];
  const float* W1  = (const float*)d_in[3];
  const float* a1s = (const float*)d_in[4];
  const float* a1n = (const float*)d_in[5];
  const float* W2  = (const float*)d_in[6];
  const float* a2s = (const float*)d_in[7];
  const float* a2n = (const float*)d_in[8];

  // Scratch carved from the A_pred region of d_out (fully overwritten by
  // k_apred, which reads only z). Round-1 layout, unchanged.
  float* out = (float*)d_out;
  float* h1   = out;                          // N*HID
  float* out1 = h1 + (size_t)N * HID;         // N*HID
  float* h2   = out1 + (size_t)N * HID;       // N*EMB
  float* f1s  = h2 + (size_t)N * EMB;         // N
  float* f1n  = f1s + N;                      // N
  float* f2s  = f1n + N;                      // N
  float* f2n  = f2s + N;                      // N
  float* mval = f2n + N;                      // N*MAXDEG
  int*   nbr  = (int*)(mval + (size_t)N * MAXDEG);  // N*MAXDEG
  int*   deg  = nbr + (size_t)N * MAXDEG;           // N
  float* z    = out + (size_t)N * N;          // output (tuple elem 1)
  float* A    = out;                          // output (tuple elem 0)

  hipLaunchKernelGGL(k_extract, dim3(N / 4), dim3(256), 0, stream, adj, Mm, nbr, mval, deg);
  hipLaunchKernelGGL(k_gemm1, dim3((N / BM) * (HID / BN)), dim3(256), 0, stream, x, W1, h1);
  hipLaunchKernelGGL(k_f1, dim3(N / 4), dim3(256), 0, stream, h1, a1s, a1n, f1s, f1n);
  hipLaunchKernelGGL(k_attn1, dim3(N), dim3(256), 0, stream, h1, f1s, f1n, nbr, mval, deg, out1);
  hipLaunchKernelGGL(k_gemm2, dim3(N / 16), dim3(256), 0, stream, out1, W2, a2s, a2n, h2, f2s, f2n);
  hipLaunchKernelGGL(k_attn2, dim3(N / 4), dim3(256), 0, stream, h2, f2s, f2n, nbr, mval, deg, z);
  hipLaunchKernelGGL(k_apred, dim3(N / 1024, N / 8), dim3(256), 0, stream, z, A);
}

// Round 5
// 212.412 us; speedup vs baseline: 1.4171x; 1.1219x over previous
//
#include <hip/hip_runtime.h>
#include <math.h>

#define N 6144
#define ATTR 512
#define HID 256
#define EMB 16
#define ALPHA 0.2f
#define MAXDEG 192
#define BM 32
#define BN 64
#define BK 32

// ---------------------------------------------------------------------------
// K1: h1 = x @ W1  [6144,512]@[512,256] fp32.  Tile 32x64, 768 blocks (3/CU).
// Per-output accumulation is BIT-IDENTICAL to the round-1 kernel (sequential
// k = 0..511, single fmac chain) — only the tiling/LDS layout changed.
// DO NOT change the accumulation order: downstream sigmoid(s-1/s) has a 0/1
// cliff at s=0 and any h1 perturbation flips near-zero dot products.
// ---------------------------------------------------------------------------
__global__ __launch_bounds__(256) void k_gemm1(const float* __restrict__ x,
                                               const float* __restrict__ W1,
                                               float* __restrict__ h1) {
  __shared__ float AsT[BK][BM + 2];  // [k][row], LD=34 (even -> float2 aligned)
  __shared__ float Bs[BK][BN + 4];   // [k][col], LD=68 (mult of 4 -> float4)
  const int ct = blockIdx.x & 3;   // HID/64 = 4 col tiles
  const int rt = blockIdx.x >> 2;  // N/32 = 192 row tiles
  const int tid = threadIdx.x;
  const int tx = tid & 15;         // col quad
  const int tyr = tid >> 4;        // row pair
  const int row0 = rt * BM, col0 = ct * BN;
  float acc[2][4] = {};
  for (int kt = 0; kt < ATTR; kt += BK) {
    {
      const int r = tid >> 3;      // 0..31
      const int kq = tid & 7;      // 0..7
      float4 v = *(const float4*)&x[(size_t)(row0 + r) * ATTR + kt + kq * 4];
      AsT[kq * 4 + 0][r] = v.x;
      AsT[kq * 4 + 1][r] = v.y;
      AsT[kq * 4 + 2][r] = v.z;
      AsT[kq * 4 + 3][r] = v.w;
    }
#pragma unroll
    for (int l = tid; l < 512; l += 256) {
      const int r = l >> 4;        // k 0..31
      const int cq = l & 15;       // col quad
      *(float4*)&Bs[r][cq * 4] =
          *(const float4*)&W1[(size_t)(kt + r) * HID + col0 + cq * 4];
    }
    __syncthreads();
#pragma unroll 8
    for (int k = 0; k < BK; ++k) {
      const float2 a = *(const float2*)&AsT[k][tyr * 2];
      const float4 b = *(const float4*)&Bs[k][tx * 4];
      acc[0][0] += a.x * b.x; acc[0][1] += a.x * b.y;
      acc[0][2] += a.x * b.z; acc[0][3] += a.x * b.w;
      acc[1][0] += a.y * b.x; acc[1][1] += a.y * b.y;
      acc[1][2] += a.y * b.z; acc[1][3] += a.y * b.w;
    }
    __syncthreads();
  }
#pragma unroll
  for (int i = 0; i < 2; ++i) {
    float4 o = {acc[i][0], acc[i][1], acc[i][2], acc[i][3]};
    *(float4*)&h1[(size_t)(row0 + tyr * 2 + i) * HID + col0 + tx * 4] = o;
  }
}

// ---------------------------------------------------------------------------
// K2: f1s[i] = h1[i,:]·a_self1 ; f1n[i] = h1[i,:]·a_neigh1   (one wave/row)
// ---------------------------------------------------------------------------
__global__ __launch_bounds__(256) void k_f1(const float* __restrict__ h1,
                                            const float* __restrict__ a_s,
                                            const float* __restrict__ a_n,
                                            float* __restrict__ f1s,
                                            float* __restrict__ f1n) {
  const int wid = (blockIdx.x * 256 + threadIdx.x) >> 6;
  const int lane = threadIdx.x & 63;
  const float* hrow = h1 + (size_t)wid * HID;
  float ss = 0.0f, sn = 0.0f;
#pragma unroll
  for (int c0 = 0; c0 < HID; c0 += 64) {
    float h = hrow[c0 + lane];
    ss += h * a_s[c0 + lane];
    sn += h * a_n[c0 + lane];
  }
#pragma unroll
  for (int off = 32; off; off >>= 1) {
    ss += __shfl_xor(ss, off);
    sn += __shfl_xor(sn, off);
  }
  if (lane == 0) { f1s[wid] = ss; f1n[wid] = sn; }
}

// ---------------------------------------------------------------------------
// K3: sparse structure extraction — one BLOCK per row, float4 loads,
//     4-wave LDS prefix keeps compaction in exact ascending index order
//     (outputs bit-identical to the wave-per-row scalar version).
// ---------------------------------------------------------------------------
__global__ __launch_bounds__(256) void k_extract(const float* __restrict__ adj,
                                                 const float* __restrict__ Mm,
                                                 int* __restrict__ nbr,
                                                 float* __restrict__ mval,
                                                 int* __restrict__ deg) {
  __shared__ int wcnt[4];
  const int i = blockIdx.x;
  const int tid = threadIdx.x;
  const int w = tid >> 6, lane = tid & 63;
  const float4* arow = (const float4*)(adj + (size_t)i * N);
  const float* mrow = Mm + (size_t)i * N;
  int* nrow = nbr + (size_t)i * MAXDEG;
  float* mout = mval + (size_t)i * MAXDEG;
  int count = 0;
#pragma unroll
  for (int r = 0; r < N / 1024; ++r) {       // 6 rounds x 1024 floats
    float4 a = arow[r * 256 + tid];          // floats r*1024 + tid*4 ..+3
    bool h0 = a.x > 0.f, h1b = a.y > 0.f, h2b = a.z > 0.f, h3b = a.w > 0.f;
    int cnt = (int)h0 + (int)h1b + (int)h2b + (int)h3b;
    unsigned long long m1 = __ballot(cnt >= 1);
    unsigned long long m2 = __ballot(cnt >= 2);
    unsigned long long m3 = __ballot(cnt >= 3);
    unsigned long long m4 = __ballot(cnt >= 4);
    int wtot = __popcll(m1) + __popcll(m2) + __popcll(m3) + __popcll(m4);
    if (lane == 0) wcnt[w] = wtot;
    __syncthreads();
    int woff = 0;
#pragma unroll
    for (int q = 0; q < 4; ++q) woff += (q < w) ? wcnt[q] : 0;
    unsigned long long lt = (1ull << lane) - 1ull;
    int pos = count + woff + __popcll(m1 & lt) + __popcll(m2 & lt) +
              __popcll(m3 & lt) + __popcll(m4 & lt);
    const int idx = r * 1024 + tid * 4;
    if (h0) { if (pos < MAXDEG) { nrow[pos] = idx;     mout[pos] = mrow[idx];     } ++pos; }
    if (h1b){ if (pos < MAXDEG) { nrow[pos] = idx + 1; mout[pos] = mrow[idx + 1]; } ++pos; }
    if (h2b){ if (pos < MAXDEG) { nrow[pos] = idx + 2; mout[pos] = mrow[idx + 2]; } ++pos; }
    if (h3b){ if (pos < MAXDEG) { nrow[pos] = idx + 3; mout[pos] = mrow[idx + 3]; } ++pos; }
    count += wcnt[0] + wcnt[1] + wcnt[2] + wcnt[3];
    __syncthreads();
  }
  if (tid == 0) deg[i] = count > MAXDEG ? MAXDEG : count;
}

// ---------------------------------------------------------------------------
// K4: sparse attention layer 1: out1[i,:] = elu( sum_j attn_ij * h1[j,:] )
// ---------------------------------------------------------------------------
__global__ __launch_bounds__(256) void k_attn1(const float* __restrict__ h1,
                                               const float* __restrict__ f1s,
                                               const float* __restrict__ f1n,
                                               const int* __restrict__ nbr,
                                               const float* __restrict__ mval,
                                               const int* __restrict__ deg,
                                               float* __restrict__ out1) {
  __shared__ float p[MAXDEG];
  __shared__ int nb[MAXDEG];
  const int i = blockIdx.x;
  const int tid = threadIdx.x;
  const int d = deg[i];
  if (d > 0 && tid < 64) {
    const float fsi = f1s[i];
    float lmax = -3.0e38f;
    for (int j = tid; j < d; j += 64) {
      int nj = nbr[(size_t)i * MAXDEG + j];
      nb[j] = nj;
      float v = (fsi + f1n[nj]) * mval[(size_t)i * MAXDEG + j];
      float e = v > 0.0f ? v : ALPHA * v;
      p[j] = e;
      lmax = fmaxf(lmax, e);
    }
#pragma unroll
    for (int off = 32; off; off >>= 1) lmax = fmaxf(lmax, __shfl_xor(lmax, off));
    float lsum = 0.0f;
    for (int j = tid; j < d; j += 64) {
      float t = expf(p[j] - lmax);
      p[j] = t;
      lsum += t;
    }
#pragma unroll
    for (int off = 32; off; off >>= 1) lsum += __shfl_xor(lsum, off);
    float inv = 1.0f / lsum;
    for (int j = tid; j < d; j += 64) p[j] *= inv;
  }
  __syncthreads();
  float acc = 0.0f;
  if (d > 0) {
    for (int j = 0; j < d; ++j) {
      acc += p[j] * h1[(size_t)nb[j] * HID + tid];
    }
  } else {
    for (int j = 0; j < N; ++j) acc += h1[(size_t)j * HID + tid];
    acc *= (1.0f / (float)N);
  }
  out1[(size_t)i * HID + tid] = acc > 0.0f ? acc : expm1f(acc);
}

// ---------------------------------------------------------------------------
// K5: h2 = out1 @ W2 ([6144,256]@[256,16]) + f2s/f2n epilogue
// ---------------------------------------------------------------------------
__global__ __launch_bounds__(256) void k_gemm2(const float* __restrict__ out1,
                                               const float* __restrict__ W2,
                                               const float* __restrict__ a_s,
                                               const float* __restrict__ a_n,
                                               float* __restrict__ h2,
                                               float* __restrict__ f2s,
                                               float* __restrict__ f2n) {
  __shared__ float Hs[16][HID + 1];
  __shared__ float Ws[HID][EMB + 1];
  const int row0 = blockIdx.x * 16;
  const int tid = threadIdx.x;
  for (int l = tid; l < 16 * HID; l += 256) {
    Hs[l >> 8][l & 255] = out1[(size_t)(row0 + (l >> 8)) * HID + (l & 255)];
  }
  for (int l = tid; l < HID * EMB; l += 256) {
    Ws[l >> 4][l & 15] = W2[l];
  }
  __syncthreads();
  const int r = tid >> 4, c = tid & 15;
  float acc = 0.0f;
  for (int k = 0; k < HID; ++k) acc += Hs[r][k] * Ws[k][c];
  h2[(size_t)(row0 + r) * EMB + c] = acc;
  float vs = acc * a_s[c], vn = acc * a_n[c];
#pragma unroll
  for (int off = 1; off < 16; off <<= 1) {
    vs += __shfl_xor(vs, off);
    vn += __shfl_xor(vn, off);
  }
  if (c == 0) { f2s[row0 + r] = vs; f2n[row0 + r] = vn; }
}

// ---------------------------------------------------------------------------
// K6: sparse attention layer 2 + elu + L2-normalize -> z  (one wave per row)
// ---------------------------------------------------------------------------
__global__ __launch_bounds__(256) void k_attn2(const float* __restrict__ h2,
                                               const float* __restrict__ f2s,
                                               const float* __restrict__ f2n,
                                               const int* __restrict__ nbr,
                                               const float* __restrict__ mval,
                                               const int* __restrict__ deg,
                                               float* __restrict__ z) {
  __shared__ float p[4][MAXDEG];
  __shared__ int nb[4][MAXDEG];
  const int w = threadIdx.x >> 6, lane = threadIdx.x & 63;
  const int i = blockIdx.x * 4 + w;
  const int d = deg[i];
  if (d > 0) {
    const float fsi = f2s[i];
    float lmax = -3.0e38f;
    for (int j = lane; j < d; j += 64) {
      int nj = nbr[(size_t)i * MAXDEG + j];
      nb[w][j] = nj;
      float v = (fsi + f2n[nj]) * mval[(size_t)i * MAXDEG + j];
      float e = v > 0.0f ? v : ALPHA * v;
      p[w][j] = e;
      lmax = fmaxf(lmax, e);
    }
#pragma unroll
    for (int off = 32; off; off >>= 1) lmax = fmaxf(lmax, __shfl_xor(lmax, off));
    float lsum = 0.0f;
    for (int j = lane; j < d; j += 64) {
      float t = expf(p[w][j] - lmax);
      p[w][j] = t;
      lsum += t;
    }
#pragma unroll
    for (int off = 32; off; off >>= 1) lsum += __shfl_xor(lsum, off);
    float inv = 1.0f / lsum;
    for (int j = lane; j < d; j += 64) p[w][j] *= inv;
  }
  __syncthreads();
  const int g = lane >> 4, c = lane & 15;
  float acc = 0.0f;
  if (d > 0) {
    for (int j = g; j < d; j += 4) {
      acc += p[w][j] * h2[(size_t)nb[w][j] * EMB + c];
    }
  } else {
    for (int j = g; j < N; j += 4) acc += h2[(size_t)j * EMB + c];
  }
  acc += __shfl_xor(acc, 16);
  acc += __shfl_xor(acc, 32);
  if (d == 0) acc *= (1.0f / (float)N);
  float val = acc > 0.0f ? acc : expm1f(acc);
  float sq = val * val;
#pragma unroll
  for (int off = 1; off < 16; off <<= 1) sq += __shfl_xor(sq, off);
  float nrm = fmaxf(sqrtf(sq), 1e-12f);
  float zv = val / nrm;
  if (lane < 16) z[(size_t)i * EMB + lane] = zv;
}

// ---------------------------------------------------------------------------
// K7: A[i,j] = sigmoid(s - 1/s), s = z_i · z_j.  8 rows x 1024 cols per block
// ---------------------------------------------------------------------------
__device__ __forceinline__ float sig_of(float s) {
  float t = s - 1.0f / s;
  return 1.0f / (1.0f + expf(-t));
}

__global__ __launch_bounds__(256) void k_apred(const float* __restrict__ z,
                                               float* __restrict__ A) {
  __shared__ float zi_s[8 * EMB];
  const int i0 = blockIdx.y * 8;
  const int tid = threadIdx.x;
  if (tid < 8 * EMB) zi_s[tid] = z[(size_t)i0 * EMB + tid];
  const int j0 = blockIdx.x * 1024 + tid * 4;
  float zj[4][EMB];
  const float4* zp = (const float4*)(z + (size_t)j0 * EMB);
#pragma unroll
  for (int q = 0; q < 4; ++q) {
#pragma unroll
    for (int kk = 0; kk < 4; ++kk) {
      float4 v = zp[q * 4 + kk];
      zj[q][kk * 4 + 0] = v.x;
      zj[q][kk * 4 + 1] = v.y;
      zj[q][kk * 4 + 2] = v.z;
      zj[q][kk * 4 + 3] = v.w;
    }
  }
  __syncthreads();
  for (int ii = 0; ii < 8; ++ii) {
    float acc0 = 0.0f, acc1 = 0.0f, acc2 = 0.0f, acc3 = 0.0f;
#pragma unroll
    for (int k = 0; k < EMB; ++k) {
      float a = zi_s[ii * EMB + k];
      acc0 += a * zj[0][k];
      acc1 += a * zj[1][k];
      acc2 += a * zj[2][k];
      acc3 += a * zj[3][k];
    }
    float4 o;
    o.x = sig_of(acc0);
    o.y = sig_of(acc1);
    o.z = sig_of(acc2);
    o.w = sig_of(acc3);
    *(float4*)(A + (size_t)(i0 + ii) * N + j0) = o;
  }
}

// ---------------------------------------------------------------------------
extern "C" void kernel_launch(void* const* d_in, const int* in_sizes, int n_in,
                              void* d_out, int out_size, void* d_ws, size_t ws_size,
                              hipStream_t stream) {
  const float* x   = (const float*)d_in[0];
  const float* adj = (const float*)d_in[1];
  const float* Mm  = (const float*)d_in[2];
  const float* W1  = (const float*)d_in[3];
  const float* a1s = (const float*)d_in[4];
  const float* a1n = (const float*)d_in[5];
  const float* W2  = (const float*)d_in[6];
  const float* a2s = (const float*)d_in[7];
  const float* a2n = (const float*)d_in[8];

  // Scratch carved from the A_pred region of d_out (fully overwritten by
  // k_apred, which reads only z). Round-1 layout, unchanged.
  float* out = (float*)d_out;
  float* h1   = out;                          // N*HID
  float* out1 = h1 + (size_t)N * HID;         // N*HID
  float* h2   = out1 + (size_t)N * HID;       // N*EMB
  float* f1s  = h2 + (size_t)N * EMB;         // N
  float* f1n  = f1s + N;                      // N
  float* f2s  = f1n + N;                      // N
  float* f2n  = f2s + N;                      // N
  float* mval = f2n + N;                      // N*MAXDEG
  int*   nbr  = (int*)(mval + (size_t)N * MAXDEG);  // N*MAXDEG
  int*   deg  = nbr + (size_t)N * MAXDEG;           // N
  float* z    = out + (size_t)N * N;          // output (tuple elem 1)
  float* A    = out;                          // output (tuple elem 0)

  hipLaunchKernelGGL(k_extract, dim3(N), dim3(256), 0, stream, adj, Mm, nbr, mval, deg);
  hipLaunchKernelGGL(k_gemm1, dim3((N / BM) * (HID / BN)), dim3(256), 0, stream, x, W1, h1);
  hipLaunchKernelGGL(k_f1, dim3(N / 4), dim3(256), 0, stream, h1, a1s, a1n, f1s, f1n);
  hipLaunchKernelGGL(k_attn1, dim3(N), dim3(256), 0, stream, h1, f1s, f1n, nbr, mval, deg, out1);
  hipLaunchKernelGGL(k_gemm2, dim3(N / 16), dim3(256), 0, stream, out1, W2, a2s, a2n, h2, f2s, f2n);
  hipLaunchKernelGGL(k_attn2, dim3(N / 4), dim3(256), 0, stream, h2, f2s, f2n, nbr, mval, deg, z);
  hipLaunchKernelGGL(k_apred, dim3(N / 1024, N / 8), dim3(256), 0, stream, z, A);
}

// Round 6
// 202.459 us; speedup vs baseline: 1.4868x; 1.0492x over previous
//
#include <hip/hip_runtime.h>
#include <math.h>

#define N 6144
#define ATTR 512
#define HID 256
#define EMB 16
#define ALPHA 0.2f
#define MAXDEG 192
#define BM 32
#define BN 64
#define BK 32

// ---------------------------------------------------------------------------
// K1: h1 = x @ W1  [6144,512]@[512,256] fp32.  Tile 32x64, 768 blocks (3/CU).
// Register-prefetch double buffer: tile kt+1's global loads issue BEFORE the
// compute on tile kt, hiding load latency under FMA work.  LDS contents per
// kt are unchanged, so the per-output accumulation chain is BIT-IDENTICAL to
// rounds 1/4/5 (sequential k = 0..511, single fmac chain).
// DO NOT change the accumulation order: downstream sigmoid(s-1/s) has a 0/1
// cliff at s=0 and any h1 perturbation flips near-zero dot products.
// ---------------------------------------------------------------------------
__global__ __launch_bounds__(256) void k_gemm1(const float* __restrict__ x,
                                               const float* __restrict__ W1,
                                               float* __restrict__ h1) {
  __shared__ float AsT[BK][BM + 2];  // [k][row], LD=34 (even -> float2 aligned)
  __shared__ float Bs[BK][BN + 4];   // [k][col], LD=68 (mult of 4 -> float4)
  const int ct = blockIdx.x & 3;   // HID/64 = 4 col tiles
  const int rt = blockIdx.x >> 2;  // N/32 = 192 row tiles
  const int tid = threadIdx.x;
  const int tx = tid & 15;         // col quad
  const int tyr = tid >> 4;        // row pair
  const int row0 = rt * BM, col0 = ct * BN;
  // staging-lane coordinates (same coverage as round-5 loops)
  const int lar = tid >> 3;        // A row 0..31
  const int lak = (tid & 7) * 4;   // A k-quad base
  const int lbk = tid >> 4;        // B k 0..15 (second half: +16)
  const int lbc = (tid & 15) * 4;  // B col-quad base
  // prefetch tile 0
  float4 pa  = *(const float4*)&x[(size_t)(row0 + lar) * ATTR + lak];
  float4 pb0 = *(const float4*)&W1[(size_t)lbk * HID + col0 + lbc];
  float4 pb1 = *(const float4*)&W1[(size_t)(lbk + 16) * HID + col0 + lbc];
  float acc[2][4] = {};
  for (int kt = 0; kt < ATTR; kt += BK) {
    AsT[lak + 0][lar] = pa.x;
    AsT[lak + 1][lar] = pa.y;
    AsT[lak + 2][lar] = pa.z;
    AsT[lak + 3][lar] = pa.w;
    *(float4*)&Bs[lbk][lbc] = pb0;
    *(float4*)&Bs[lbk + 16][lbc] = pb1;
    __syncthreads();
    if (kt + BK < ATTR) {  // issue next tile's loads; latency hides under FMA
      pa  = *(const float4*)&x[(size_t)(row0 + lar) * ATTR + kt + BK + lak];
      pb0 = *(const float4*)&W1[(size_t)(kt + BK + lbk) * HID + col0 + lbc];
      pb1 = *(const float4*)&W1[(size_t)(kt + BK + lbk + 16) * HID + col0 + lbc];
    }
#pragma unroll 8
    for (int k = 0; k < BK; ++k) {
      const float2 a = *(const float2*)&AsT[k][tyr * 2];
      const float4 b = *(const float4*)&Bs[k][tx * 4];
      acc[0][0] += a.x * b.x; acc[0][1] += a.x * b.y;
      acc[0][2] += a.x * b.z; acc[0][3] += a.x * b.w;
      acc[1][0] += a.y * b.x; acc[1][1] += a.y * b.y;
      acc[1][2] += a.y * b.z; acc[1][3] += a.y * b.w;
    }
    __syncthreads();
  }
#pragma unroll
  for (int i = 0; i < 2; ++i) {
    float4 o = {acc[i][0], acc[i][1], acc[i][2], acc[i][3]};
    *(float4*)&h1[(size_t)(row0 + tyr * 2 + i) * HID + col0 + tx * 4] = o;
  }
}

// ---------------------------------------------------------------------------
// K2: f1s[i] = h1[i,:]·a_self1 ; f1n[i] = h1[i,:]·a_neigh1   (one wave/row)
// ---------------------------------------------------------------------------
__global__ __launch_bounds__(256) void k_f1(const float* __restrict__ h1,
                                            const float* __restrict__ a_s,
                                            const float* __restrict__ a_n,
                                            float* __restrict__ f1s,
                                            float* __restrict__ f1n) {
  const int wid = (blockIdx.x * 256 + threadIdx.x) >> 6;
  const int lane = threadIdx.x & 63;
  const float* hrow = h1 + (size_t)wid * HID;
  float ss = 0.0f, sn = 0.0f;
#pragma unroll
  for (int c0 = 0; c0 < HID; c0 += 64) {
    float h = hrow[c0 + lane];
    ss += h * a_s[c0 + lane];
    sn += h * a_n[c0 + lane];
  }
#pragma unroll
  for (int off = 32; off; off >>= 1) {
    ss += __shfl_xor(ss, off);
    sn += __shfl_xor(sn, off);
  }
  if (lane == 0) { f1s[wid] = ss; f1n[wid] = sn; }
}

// ---------------------------------------------------------------------------
// K3: sparse structure extraction — one BLOCK per row.  All 6 adj float4
// loads are hoisted into registers BEFORE the compaction rounds (no
// inter-round load dependence; barriers otherwise pin loads serially).
// Outputs bit-identical to rounds 4/5.
// ---------------------------------------------------------------------------
__global__ __launch_bounds__(256) void k_extract(const float* __restrict__ adj,
                                                 const float* __restrict__ Mm,
                                                 int* __restrict__ nbr,
                                                 float* __restrict__ mval,
                                                 int* __restrict__ deg) {
  __shared__ int wcnt[4];
  const int i = blockIdx.x;
  const int tid = threadIdx.x;
  const int w = tid >> 6, lane = tid & 63;
  const float4* arow = (const float4*)(adj + (size_t)i * N);
  const float* mrow = Mm + (size_t)i * N;
  int* nrow = nbr + (size_t)i * MAXDEG;
  float* mout = mval + (size_t)i * MAXDEG;
  float4 av[N / 1024];
#pragma unroll
  for (int r = 0; r < N / 1024; ++r) av[r] = arow[r * 256 + tid];
  int count = 0;
#pragma unroll
  for (int r = 0; r < N / 1024; ++r) {       // 6 rounds x 1024 floats
    const float4 a = av[r];
    bool h0 = a.x > 0.f, h1b = a.y > 0.f, h2b = a.z > 0.f, h3b = a.w > 0.f;
    int cnt = (int)h0 + (int)h1b + (int)h2b + (int)h3b;
    unsigned long long m1 = __ballot(cnt >= 1);
    unsigned long long m2 = __ballot(cnt >= 2);
    unsigned long long m3 = __ballot(cnt >= 3);
    unsigned long long m4 = __ballot(cnt >= 4);
    int wtot = __popcll(m1) + __popcll(m2) + __popcll(m3) + __popcll(m4);
    if (lane == 0) wcnt[w] = wtot;
    __syncthreads();
    int woff = 0;
#pragma unroll
    for (int q = 0; q < 4; ++q) woff += (q < w) ? wcnt[q] : 0;
    unsigned long long lt = (1ull << lane) - 1ull;
    int pos = count + woff + __popcll(m1 & lt) + __popcll(m2 & lt) +
              __popcll(m3 & lt) + __popcll(m4 & lt);
    const int idx = r * 1024 + tid * 4;
    if (h0) { if (pos < MAXDEG) { nrow[pos] = idx;     mout[pos] = mrow[idx];     } ++pos; }
    if (h1b){ if (pos < MAXDEG) { nrow[pos] = idx + 1; mout[pos] = mrow[idx + 1]; } ++pos; }
    if (h2b){ if (pos < MAXDEG) { nrow[pos] = idx + 2; mout[pos] = mrow[idx + 2]; } ++pos; }
    if (h3b){ if (pos < MAXDEG) { nrow[pos] = idx + 3; mout[pos] = mrow[idx + 3]; } ++pos; }
    count += wcnt[0] + wcnt[1] + wcnt[2] + wcnt[3];
    __syncthreads();
  }
  if (tid == 0) deg[i] = count > MAXDEG ? MAXDEG : count;
}

// ---------------------------------------------------------------------------
// K4: sparse attention layer 1: out1[i,:] = elu( sum_j attn_ij * h1[j,:] )
// ---------------------------------------------------------------------------
__global__ __launch_bounds__(256) void k_attn1(const float* __restrict__ h1,
                                               const float* __restrict__ f1s,
                                               const float* __restrict__ f1n,
                                               const int* __restrict__ nbr,
                                               const float* __restrict__ mval,
                                               const int* __restrict__ deg,
                                               float* __restrict__ out1) {
  __shared__ float p[MAXDEG];
  __shared__ int nb[MAXDEG];
  const int i = blockIdx.x;
  const int tid = threadIdx.x;
  const int d = deg[i];
  if (d > 0 && tid < 64) {
    const float fsi = f1s[i];
    float lmax = -3.0e38f;
    for (int j = tid; j < d; j += 64) {
      int nj = nbr[(size_t)i * MAXDEG + j];
      nb[j] = nj;
      float v = (fsi + f1n[nj]) * mval[(size_t)i * MAXDEG + j];
      float e = v > 0.0f ? v : ALPHA * v;
      p[j] = e;
      lmax = fmaxf(lmax, e);
    }
#pragma unroll
    for (int off = 32; off; off >>= 1) lmax = fmaxf(lmax, __shfl_xor(lmax, off));
    float lsum = 0.0f;
    for (int j = tid; j < d; j += 64) {
      float t = expf(p[j] - lmax);
      p[j] = t;
      lsum += t;
    }
#pragma unroll
    for (int off = 32; off; off >>= 1) lsum += __shfl_xor(lsum, off);
    float inv = 1.0f / lsum;
    for (int j = tid; j < d; j += 64) p[j] *= inv;
  }
  __syncthreads();
  float acc = 0.0f;
  if (d > 0) {
    for (int j = 0; j < d; ++j) {
      acc += p[j] * h1[(size_t)nb[j] * HID + tid];
    }
  } else {
    for (int j = 0; j < N; ++j) acc += h1[(size_t)j * HID + tid];
    acc *= (1.0f / (float)N);
  }
  out1[(size_t)i * HID + tid] = acc > 0.0f ? acc : expm1f(acc);
}

// ---------------------------------------------------------------------------
// K5: h2 = out1 @ W2 ([6144,256]@[256,16]) + f2s/f2n epilogue
// ---------------------------------------------------------------------------
__global__ __launch_bounds__(256) void k_gemm2(const float* __restrict__ out1,
                                               const float* __restrict__ W2,
                                               const float* __restrict__ a_s,
                                               const float* __restrict__ a_n,
                                               float* __restrict__ h2,
                                               float* __restrict__ f2s,
                                               float* __restrict__ f2n) {
  __shared__ float Hs[16][HID + 1];
  __shared__ float Ws[HID][EMB + 1];
  const int row0 = blockIdx.x * 16;
  const int tid = threadIdx.x;
  for (int l = tid; l < 16 * HID; l += 256) {
    Hs[l >> 8][l & 255] = out1[(size_t)(row0 + (l >> 8)) * HID + (l & 255)];
  }
  for (int l = tid; l < HID * EMB; l += 256) {
    Ws[l >> 4][l & 15] = W2[l];
  }
  __syncthreads();
  const int r = tid >> 4, c = tid & 15;
  float acc = 0.0f;
  for (int k = 0; k < HID; ++k) acc += Hs[r][k] * Ws[k][c];
  h2[(size_t)(row0 + r) * EMB + c] = acc;
  float vs = acc * a_s[c], vn = acc * a_n[c];
#pragma unroll
  for (int off = 1; off < 16; off <<= 1) {
    vs += __shfl_xor(vs, off);
    vn += __shfl_xor(vn, off);
  }
  if (c == 0) { f2s[row0 + r] = vs; f2n[row0 + r] = vn; }
}

// ---------------------------------------------------------------------------
// K6: sparse attention layer 2 + elu + L2-normalize -> z  (one wave per row)
// ---------------------------------------------------------------------------
__global__ __launch_bounds__(256) void k_attn2(const float* __restrict__ h2,
                                               const float* __restrict__ f2s,
                                               const float* __restrict__ f2n,
                                               const int* __restrict__ nbr,
                                               const float* __restrict__ mval,
                                               const int* __restrict__ deg,
                                               float* __restrict__ z) {
  __shared__ float p[4][MAXDEG];
  __shared__ int nb[4][MAXDEG];
  const int w = threadIdx.x >> 6, lane = threadIdx.x & 63;
  const int i = blockIdx.x * 4 + w;
  const int d = deg[i];
  if (d > 0) {
    const float fsi = f2s[i];
    float lmax = -3.0e38f;
    for (int j = lane; j < d; j += 64) {
      int nj = nbr[(size_t)i * MAXDEG + j];
      nb[w][j] = nj;
      float v = (fsi + f2n[nj]) * mval[(size_t)i * MAXDEG + j];
      float e = v > 0.0f ? v : ALPHA * v;
      p[w][j] = e;
      lmax = fmaxf(lmax, e);
    }
#pragma unroll
    for (int off = 32; off; off >>= 1) lmax = fmaxf(lmax, __shfl_xor(lmax, off));
    float lsum = 0.0f;
    for (int j = lane; j < d; j += 64) {
      float t = expf(p[w][j] - lmax);
      p[w][j] = t;
      lsum += t;
    }
#pragma unroll
    for (int off = 32; off; off >>= 1) lsum += __shfl_xor(lsum, off);
    float inv = 1.0f / lsum;
    for (int j = lane; j < d; j += 64) p[w][j] *= inv;
  }
  __syncthreads();
  const int g = lane >> 4, c = lane & 15;
  float acc = 0.0f;
  if (d > 0) {
    for (int j = g; j < d; j += 4) {
      acc += p[w][j] * h2[(size_t)nb[w][j] * EMB + c];
    }
  } else {
    for (int j = g; j < N; j += 4) acc += h2[(size_t)j * EMB + c];
  }
  acc += __shfl_xor(acc, 16);
  acc += __shfl_xor(acc, 32);
  if (d == 0) acc *= (1.0f / (float)N);
  float val = acc > 0.0f ? acc : expm1f(acc);
  float sq = val * val;
#pragma unroll
  for (int off = 1; off < 16; off <<= 1) sq += __shfl_xor(sq, off);
  float nrm = fmaxf(sqrtf(sq), 1e-12f);
  float zv = val / nrm;
  if (lane < 16) z[(size_t)i * EMB + lane] = zv;
}

// ---------------------------------------------------------------------------
// K7: A[i,j] = sigmoid(s - 1/s), s = z_i · z_j.  8 rows x 1024 cols per block
// ---------------------------------------------------------------------------
__device__ __forceinline__ float sig_of(float s) {
  float t = s - 1.0f / s;
  return 1.0f / (1.0f + expf(-t));
}

__global__ __launch_bounds__(256) void k_apred(const float* __restrict__ z,
                                               float* __restrict__ A) {
  __shared__ float zi_s[8 * EMB];
  const int i0 = blockIdx.y * 8;
  const int tid = threadIdx.x;
  if (tid < 8 * EMB) zi_s[tid] = z[(size_t)i0 * EMB + tid];
  const int j0 = blockIdx.x * 1024 + tid * 4;
  float zj[4][EMB];
  const float4* zp = (const float4*)(z + (size_t)j0 * EMB);
#pragma unroll
  for (int q = 0; q < 4; ++q) {
#pragma unroll
    for (int kk = 0; kk < 4; ++kk) {
      float4 v = zp[q * 4 + kk];
      zj[q][kk * 4 + 0] = v.x;
      zj[q][kk * 4 + 1] = v.y;
      zj[q][kk * 4 + 2] = v.z;
      zj[q][kk * 4 + 3] = v.w;
    }
  }
  __syncthreads();
  for (int ii = 0; ii < 8; ++ii) {
    float acc0 = 0.0f, acc1 = 0.0f, acc2 = 0.0f, acc3 = 0.0f;
#pragma unroll
    for (int k = 0; k < EMB; ++k) {
      float a = zi_s[ii * EMB + k];
      acc0 += a * zj[0][k];
      acc1 += a * zj[1][k];
      acc2 += a * zj[2][k];
      acc3 += a * zj[3][k];
    }
    float4 o;
    o.x = sig_of(acc0);
    o.y = sig_of(acc1);
    o.z = sig_of(acc2);
    o.w = sig_of(acc3);
    *(float4*)(A + (size_t)(i0 + ii) * N + j0) = o;
  }
}

// ---------------------------------------------------------------------------
extern "C" void kernel_launch(void* const* d_in, const int* in_sizes, int n_in,
                              void* d_out, int out_size, void* d_ws, size_t ws_size,
                              hipStream_t stream) {
  const float* x   = (const float*)d_in[0];
  const float* adj = (const float*)d_in[1];
  const float* Mm  = (const float*)d_in[2];
  const float* W1  = (const float*)d_in[3];
  const float* a1s = (const float*)d_in[4];
  const float* a1n = (const float*)d_in[5];
  const float* W2  = (const float*)d_in[6];
  const float* a2s = (const float*)d_in[7];
  const float* a2n = (const float*)d_in[8];

  // Scratch carved from the A_pred region of d_out (fully overwritten by
  // k_apred, which reads only z). Round-1 layout, unchanged.
  float* out = (float*)d_out;
  float* h1   = out;                          // N*HID
  float* out1 = h1 + (size_t)N * HID;         // N*HID
  float* h2   = out1 + (size_t)N * HID;       // N*EMB
  float* f1s  = h2 + (size_t)N * EMB;         // N
  float* f1n  = f1s + N;                      // N
  float* f2s  = f1n + N;                      // N
  float* f2n  = f2s + N;                      // N
  float* mval = f2n + N;                      // N*MAXDEG
  int*   nbr  = (int*)(mval + (size_t)N * MAXDEG);  // N*MAXDEG
  int*   deg  = nbr + (size_t)N * MAXDEG;           // N
  float* z    = out + (size_t)N * N;          // output (tuple elem 1)
  float* A    = out;                          // output (tuple elem 0)

  hipLaunchKernelGGL(k_extract, dim3(N), dim3(256), 0, stream, adj, Mm, nbr, mval, deg);
  hipLaunchKernelGGL(k_gemm1, dim3((N / BM) * (HID / BN)), dim3(256), 0, stream, x, W1, h1);
  hipLaunchKernelGGL(k_f1, dim3(N / 4), dim3(256), 0, stream, h1, a1s, a1n, f1s, f1n);
  hipLaunchKernelGGL(k_attn1, dim3(N), dim3(256), 0, stream, h1, f1s, f1n, nbr, mval, deg, out1);
  hipLaunchKernelGGL(k_gemm2, dim3(N / 16), dim3(256), 0, stream, out1, W2, a2s, a2n, h2, f2s, f2n);
  hipLaunchKernelGGL(k_attn2, dim3(N / 4), dim3(256), 0, stream, h2, f2s, f2n, nbr, mval, deg, z);
  hipLaunchKernelGGL(k_apred, dim3(N / 1024, N / 8), dim3(256), 0, stream, z, A);
}

// Round 7
// 199.889 us; speedup vs baseline: 1.5059x; 1.0129x over previous
//
#include <hip/hip_runtime.h>
#include <math.h>

#define N 6144
#define ATTR 512
#define HID 256
#define EMB 16
#define ALPHA 0.2f
#define MAXDEG 192
#define BK 32

// ---------------------------------------------------------------------------
// K1: h1 = x @ W1  [6144,512]@[512,256] fp32.
// Tile 32 rows x 64 cols, 128 threads, 4x4 acc/thread -> per k-step each
// thread does 2x ds_read_b128 for 16 FMAs (vs b64+b128 per 8 before: halves
// LDS-pipe cycles per FLOP, the measured bottleneck).  Grid 192x4 = 768
// blocks = 3.0/CU exactly (balanced).  Double-buffered LDS, register
// prefetch, ONE barrier per K-tile.
// Per-output accumulation is BIT-IDENTICAL to rounds 1/4/5/6 (sequential
// k = 0..511, single fmac chain).  DO NOT change the accumulation order:
// downstream sigmoid(s-1/s) has a 0/1 cliff at s=0 and any h1 perturbation
// flips near-zero dot products.
// ---------------------------------------------------------------------------
__global__ __launch_bounds__(128) void k_gemm1(const float* __restrict__ x,
                                               const float* __restrict__ W1,
                                               float* __restrict__ h1) {
  __shared__ float AsT[2][BK][36];   // [buf][k][row], LD=36 (16B-aligned rows)
  __shared__ float Bs[2][BK][68];    // [buf][k][col], LD=68
  const int ct = blockIdx.x & 3;     // HID/64 = 4 col tiles
  const int rt = blockIdx.x >> 2;    // N/32 = 192 row tiles
  const int tid = threadIdx.x;       // 0..127
  const int tx = tid & 15;           // col quad
  const int ty = tid >> 4;           // row quad 0..7
  const int row0 = rt * 32, col0 = ct * 64;
  // staging coords: A tile 32r x 32k = 256 float4 (2/thread);
  //                 B tile 32k x 64c = 512 float4 (4/thread)
  const int ar0 = tid >> 3;          // 0..15  (second: +16)
  const int akq = (tid & 7) * 4;     // k base
  const int bk0 = tid >> 4;          // 0..7   (others: +8,+16,+24)
  const int bcq = (tid & 15) * 4;    // col base
  float4 pa0 = *(const float4*)&x[(size_t)(row0 + ar0) * ATTR + akq];
  float4 pa1 = *(const float4*)&x[(size_t)(row0 + ar0 + 16) * ATTR + akq];
  float4 pb0 = *(const float4*)&W1[(size_t)bk0 * HID + col0 + bcq];
  float4 pb1 = *(const float4*)&W1[(size_t)(bk0 + 8) * HID + col0 + bcq];
  float4 pb2 = *(const float4*)&W1[(size_t)(bk0 + 16) * HID + col0 + bcq];
  float4 pb3 = *(const float4*)&W1[(size_t)(bk0 + 24) * HID + col0 + bcq];
  float acc[4][4] = {};
  int buf = 0;
  for (int kt = 0; kt < ATTR; kt += BK) {
    AsT[buf][akq + 0][ar0] = pa0.x;
    AsT[buf][akq + 1][ar0] = pa0.y;
    AsT[buf][akq + 2][ar0] = pa0.z;
    AsT[buf][akq + 3][ar0] = pa0.w;
    AsT[buf][akq + 0][ar0 + 16] = pa1.x;
    AsT[buf][akq + 1][ar0 + 16] = pa1.y;
    AsT[buf][akq + 2][ar0 + 16] = pa1.z;
    AsT[buf][akq + 3][ar0 + 16] = pa1.w;
    *(float4*)&Bs[buf][bk0][bcq] = pb0;
    *(float4*)&Bs[buf][bk0 + 8][bcq] = pb1;
    *(float4*)&Bs[buf][bk0 + 16][bcq] = pb2;
    *(float4*)&Bs[buf][bk0 + 24][bcq] = pb3;
    __syncthreads();
    if (kt + BK < ATTR) {  // next tile's loads hide under the FMA loop
      pa0 = *(const float4*)&x[(size_t)(row0 + ar0) * ATTR + kt + BK + akq];
      pa1 = *(const float4*)&x[(size_t)(row0 + ar0 + 16) * ATTR + kt + BK + akq];
      pb0 = *(const float4*)&W1[(size_t)(kt + BK + bk0) * HID + col0 + bcq];
      pb1 = *(const float4*)&W1[(size_t)(kt + BK + bk0 + 8) * HID + col0 + bcq];
      pb2 = *(const float4*)&W1[(size_t)(kt + BK + bk0 + 16) * HID + col0 + bcq];
      pb3 = *(const float4*)&W1[(size_t)(kt + BK + bk0 + 24) * HID + col0 + bcq];
    }
#pragma unroll 8
    for (int k = 0; k < BK; ++k) {
      const float4 a = *(const float4*)&AsT[buf][k][ty * 4];
      const float4 b = *(const float4*)&Bs[buf][k][tx * 4];
      acc[0][0] += a.x * b.x; acc[0][1] += a.x * b.y; acc[0][2] += a.x * b.z; acc[0][3] += a.x * b.w;
      acc[1][0] += a.y * b.x; acc[1][1] += a.y * b.y; acc[1][2] += a.y * b.z; acc[1][3] += a.y * b.w;
      acc[2][0] += a.z * b.x; acc[2][1] += a.z * b.y; acc[2][2] += a.z * b.z; acc[2][3] += a.z * b.w;
      acc[3][0] += a.w * b.x; acc[3][1] += a.w * b.y; acc[3][2] += a.w * b.z; acc[3][3] += a.w * b.w;
    }
    buf ^= 1;
  }
#pragma unroll
  for (int i = 0; i < 4; ++i) {
    float4 o = {acc[i][0], acc[i][1], acc[i][2], acc[i][3]};
    *(float4*)&h1[(size_t)(row0 + ty * 4 + i) * HID + col0 + tx * 4] = o;
  }
}

// ---------------------------------------------------------------------------
// K2: f1s[i] = h1[i,:]·a_self1 ; f1n[i] = h1[i,:]·a_neigh1   (one wave/row)
// ---------------------------------------------------------------------------
__global__ __launch_bounds__(256) void k_f1(const float* __restrict__ h1,
                                            const float* __restrict__ a_s,
                                            const float* __restrict__ a_n,
                                            float* __restrict__ f1s,
                                            float* __restrict__ f1n) {
  const int wid = (blockIdx.x * 256 + threadIdx.x) >> 6;
  const int lane = threadIdx.x & 63;
  const float* hrow = h1 + (size_t)wid * HID;
  float ss = 0.0f, sn = 0.0f;
#pragma unroll
  for (int c0 = 0; c0 < HID; c0 += 64) {
    float h = hrow[c0 + lane];
    ss += h * a_s[c0 + lane];
    sn += h * a_n[c0 + lane];
  }
#pragma unroll
  for (int off = 32; off; off >>= 1) {
    ss += __shfl_xor(ss, off);
    sn += __shfl_xor(sn, off);
  }
  if (lane == 0) { f1s[wid] = ss; f1n[wid] = sn; }
}

// ---------------------------------------------------------------------------
// K3: sparse structure extraction — one BLOCK per row, ONE barrier total.
// Phase 1: all loads hoisted, all 24 ballots + per-wave counts -> LDS.
// Phase 2 (after the single sync): compaction writes from registers + count
// table.  Output order/values bit-identical to rounds 4/5/6.
// ---------------------------------------------------------------------------
__global__ __launch_bounds__(256) void k_extract(const float* __restrict__ adj,
                                                 const float* __restrict__ Mm,
                                                 int* __restrict__ nbr,
                                                 float* __restrict__ mval,
                                                 int* __restrict__ deg) {
  __shared__ int wcnt[N / 1024][4];
  const int i = blockIdx.x;
  const int tid = threadIdx.x;
  const int w = tid >> 6, lane = tid & 63;
  const float4* arow = (const float4*)(adj + (size_t)i * N);
  const float* mrow = Mm + (size_t)i * N;
  int* nrow = nbr + (size_t)i * MAXDEG;
  float* mout = mval + (size_t)i * MAXDEG;
  float4 av[N / 1024];
#pragma unroll
  for (int r = 0; r < N / 1024; ++r) av[r] = arow[r * 256 + tid];
  unsigned long long m1[N / 1024], m2[N / 1024], m3[N / 1024], m4[N / 1024];
#pragma unroll
  for (int r = 0; r < N / 1024; ++r) {
    const float4 a = av[r];
    bool h0 = a.x > 0.f, h1b = a.y > 0.f, h2b = a.z > 0.f, h3b = a.w > 0.f;
    int cnt = (int)h0 + (int)h1b + (int)h2b + (int)h3b;
    m1[r] = __ballot(cnt >= 1);
    m2[r] = __ballot(cnt >= 2);
    m3[r] = __ballot(cnt >= 3);
    m4[r] = __ballot(cnt >= 4);
    if (lane == 0) {
      wcnt[r][w] = __popcll(m1[r]) + __popcll(m2[r]) + __popcll(m3[r]) + __popcll(m4[r]);
    }
  }
  __syncthreads();
  const unsigned long long lt = (1ull << lane) - 1ull;
  int count = 0;
#pragma unroll
  for (int r = 0; r < N / 1024; ++r) {
    const float4 a = av[r];
    bool h0 = a.x > 0.f, h1b = a.y > 0.f, h2b = a.z > 0.f, h3b = a.w > 0.f;
    int woff = 0;
#pragma unroll
    for (int q = 0; q < 4; ++q) woff += (q < w) ? wcnt[r][q] : 0;
    int pos = count + woff + __popcll(m1[r] & lt) + __popcll(m2[r] & lt) +
              __popcll(m3[r] & lt) + __popcll(m4[r] & lt);
    const int idx = r * 1024 + tid * 4;
    if (h0) { if (pos < MAXDEG) { nrow[pos] = idx;     mout[pos] = mrow[idx];     } ++pos; }
    if (h1b){ if (pos < MAXDEG) { nrow[pos] = idx + 1; mout[pos] = mrow[idx + 1]; } ++pos; }
    if (h2b){ if (pos < MAXDEG) { nrow[pos] = idx + 2; mout[pos] = mrow[idx + 2]; } ++pos; }
    if (h3b){ if (pos < MAXDEG) { nrow[pos] = idx + 3; mout[pos] = mrow[idx + 3]; } ++pos; }
    count += wcnt[r][0] + wcnt[r][1] + wcnt[r][2] + wcnt[r][3];
  }
  if (tid == 0) deg[i] = count > MAXDEG ? MAXDEG : count;
}

// ---------------------------------------------------------------------------
// K4: sparse attention layer 1: out1[i,:] = elu( sum_j attn_ij * h1[j,:] )
// ---------------------------------------------------------------------------
__global__ __launch_bounds__(256) void k_attn1(const float* __restrict__ h1,
                                               const float* __restrict__ f1s,
                                               const float* __restrict__ f1n,
                                               const int* __restrict__ nbr,
                                               const float* __restrict__ mval,
                                               const int* __restrict__ deg,
                                               float* __restrict__ out1) {
  __shared__ float p[MAXDEG];
  __shared__ int nb[MAXDEG];
  const int i = blockIdx.x;
  const int tid = threadIdx.x;
  const int d = deg[i];
  if (d > 0 && tid < 64) {
    const float fsi = f1s[i];
    float lmax = -3.0e38f;
    for (int j = tid; j < d; j += 64) {
      int nj = nbr[(size_t)i * MAXDEG + j];
      nb[j] = nj;
      float v = (fsi + f1n[nj]) * mval[(size_t)i * MAXDEG + j];
      float e = v > 0.0f ? v : ALPHA * v;
      p[j] = e;
      lmax = fmaxf(lmax, e);
    }
#pragma unroll
    for (int off = 32; off; off >>= 1) lmax = fmaxf(lmax, __shfl_xor(lmax, off));
    float lsum = 0.0f;
    for (int j = tid; j < d; j += 64) {
      float t = expf(p[j] - lmax);
      p[j] = t;
      lsum += t;
    }
#pragma unroll
    for (int off = 32; off; off >>= 1) lsum += __shfl_xor(lsum, off);
    float inv = 1.0f / lsum;
    for (int j = tid; j < d; j += 64) p[j] *= inv;
  }
  __syncthreads();
  float acc = 0.0f;
  if (d > 0) {
    for (int j = 0; j < d; ++j) {
      acc += p[j] * h1[(size_t)nb[j] * HID + tid];
    }
  } else {
    for (int j = 0; j < N; ++j) acc += h1[(size_t)j * HID + tid];
    acc *= (1.0f / (float)N);
  }
  out1[(size_t)i * HID + tid] = acc > 0.0f ? acc : expm1f(acc);
}

// ---------------------------------------------------------------------------
// K5: h2 = out1 @ W2 ([6144,256]@[256,16]) + f2s/f2n epilogue
// ---------------------------------------------------------------------------
__global__ __launch_bounds__(256) void k_gemm2(const float* __restrict__ out1,
                                               const float* __restrict__ W2,
                                               const float* __restrict__ a_s,
                                               const float* __restrict__ a_n,
                                               float* __restrict__ h2,
                                               float* __restrict__ f2s,
                                               float* __restrict__ f2n) {
  __shared__ float Hs[16][HID + 1];
  __shared__ float Ws[HID][EMB + 1];
  const int row0 = blockIdx.x * 16;
  const int tid = threadIdx.x;
  for (int l = tid; l < 16 * HID; l += 256) {
    Hs[l >> 8][l & 255] = out1[(size_t)(row0 + (l >> 8)) * HID + (l & 255)];
  }
  for (int l = tid; l < HID * EMB; l += 256) {
    Ws[l >> 4][l & 15] = W2[l];
  }
  __syncthreads();
  const int r = tid >> 4, c = tid & 15;
  float acc = 0.0f;
  for (int k = 0; k < HID; ++k) acc += Hs[r][k] * Ws[k][c];
  h2[(size_t)(row0 + r) * EMB + c] = acc;
  float vs = acc * a_s[c], vn = acc * a_n[c];
#pragma unroll
  for (int off = 1; off < 16; off <<= 1) {
    vs += __shfl_xor(vs, off);
    vn += __shfl_xor(vn, off);
  }
  if (c == 0) { f2s[row0 + r] = vs; f2n[row0 + r] = vn; }
}

// ---------------------------------------------------------------------------
// K6: sparse attention layer 2 + elu + L2-normalize -> z  (one wave per row)
// ---------------------------------------------------------------------------
__global__ __launch_bounds__(256) void k_attn2(const float* __restrict__ h2,
                                               const float* __restrict__ f2s,
                                               const float* __restrict__ f2n,
                                               const int* __restrict__ nbr,
                                               const float* __restrict__ mval,
                                               const int* __restrict__ deg,
                                               float* __restrict__ z) {
  __shared__ float p[4][MAXDEG];
  __shared__ int nb[4][MAXDEG];
  const int w = threadIdx.x >> 6, lane = threadIdx.x & 63;
  const int i = blockIdx.x * 4 + w;
  const int d = deg[i];
  if (d > 0) {
    const float fsi = f2s[i];
    float lmax = -3.0e38f;
    for (int j = lane; j < d; j += 64) {
      int nj = nbr[(size_t)i * MAXDEG + j];
      nb[w][j] = nj;
      float v = (fsi + f2n[nj]) * mval[(size_t)i * MAXDEG + j];
      float e = v > 0.0f ? v : ALPHA * v;
      p[w][j] = e;
      lmax = fmaxf(lmax, e);
    }
#pragma unroll
    for (int off = 32; off; off >>= 1) lmax = fmaxf(lmax, __shfl_xor(lmax, off));
    float lsum = 0.0f;
    for (int j = lane; j < d; j += 64) {
      float t = expf(p[w][j] - lmax);
      p[w][j] = t;
      lsum += t;
    }
#pragma unroll
    for (int off = 32; off; off >>= 1) lsum += __shfl_xor(lsum, off);
    float inv = 1.0f / lsum;
    for (int j = lane; j < d; j += 64) p[w][j] *= inv;
  }
  __syncthreads();
  const int g = lane >> 4, c = lane & 15;
  float acc = 0.0f;
  if (d > 0) {
    for (int j = g; j < d; j += 4) {
      acc += p[w][j] * h2[(size_t)nb[w][j] * EMB + c];
    }
  } else {
    for (int j = g; j < N; j += 4) acc += h2[(size_t)j * EMB + c];
  }
  acc += __shfl_xor(acc, 16);
  acc += __shfl_xor(acc, 32);
  if (d == 0) acc *= (1.0f / (float)N);
  float val = acc > 0.0f ? acc : expm1f(acc);
  float sq = val * val;
#pragma unroll
  for (int off = 1; off < 16; off <<= 1) sq += __shfl_xor(sq, off);
  float nrm = fmaxf(sqrtf(sq), 1e-12f);
  float zv = val / nrm;
  if (lane < 16) z[(size_t)i * EMB + lane] = zv;
}

// ---------------------------------------------------------------------------
// K7: A[i,j] = sigmoid(s - 1/s), s = z_i · z_j.  8 rows x 1024 cols per block
// ---------------------------------------------------------------------------
__device__ __forceinline__ float sig_of(float s) {
  float t = s - 1.0f / s;
  return 1.0f / (1.0f + expf(-t));
}

__global__ __launch_bounds__(256) void k_apred(const float* __restrict__ z,
                                               float* __restrict__ A) {
  __shared__ float zi_s[8 * EMB];
  const int i0 = blockIdx.y * 8;
  const int tid = threadIdx.x;
  if (tid < 8 * EMB) zi_s[tid] = z[(size_t)i0 * EMB + tid];
  const int j0 = blockIdx.x * 1024 + tid * 4;
  float zj[4][EMB];
  const float4* zp = (const float4*)(z + (size_t)j0 * EMB);
#pragma unroll
  for (int q = 0; q < 4; ++q) {
#pragma unroll
    for (int kk = 0; kk < 4; ++kk) {
      float4 v = zp[q * 4 + kk];
      zj[q][kk * 4 + 0] = v.x;
      zj[q][kk * 4 + 1] = v.y;
      zj[q][kk * 4 + 2] = v.z;
      zj[q][kk * 4 + 3] = v.w;
    }
  }
  __syncthreads();
  for (int ii = 0; ii < 8; ++ii) {
    float acc0 = 0.0f, acc1 = 0.0f, acc2 = 0.0f, acc3 = 0.0f;
#pragma unroll
    for (int k = 0; k < EMB; ++k) {
      float a = zi_s[ii * EMB + k];
      acc0 += a * zj[0][k];
      acc1 += a * zj[1][k];
      acc2 += a * zj[2][k];
      acc3 += a * zj[3][k];
    }
    float4 o;
    o.x = sig_of(acc0);
    o.y = sig_of(acc1);
    o.z = sig_of(acc2);
    o.w = sig_of(acc3);
    *(float4*)(A + (size_t)(i0 + ii) * N + j0) = o;
  }
}

// ---------------------------------------------------------------------------
extern "C" void kernel_launch(void* const* d_in, const int* in_sizes, int n_in,
                              void* d_out, int out_size, void* d_ws, size_t ws_size,
                              hipStream_t stream) {
  const float* x   = (const float*)d_in[0];
  const float* adj = (const float*)d_in[1];
  const float* Mm  = (const float*)d_in[2];
  const float* W1  = (const float*)d_in[3];
  const float* a1s = (const float*)d_in[4];
  const float* a1n = (const float*)d_in[5];
  const float* W2  = (const float*)d_in[6];
  const float* a2s = (const float*)d_in[7];
  const float* a2n = (const float*)d_in[8];

  // Scratch carved from the A_pred region of d_out (fully overwritten by
  // k_apred, which reads only z). Round-1 layout, unchanged.
  float* out = (float*)d_out;
  float* h1   = out;                          // N*HID
  float* out1 = h1 + (size_t)N * HID;         // N*HID
  float* h2   = out1 + (size_t)N * HID;       // N*EMB
  float* f1s  = h2 + (size_t)N * EMB;         // N
  float* f1n  = f1s + N;                      // N
  float* f2s  = f1n + N;                      // N
  float* f2n  = f2s + N;                      // N
  float* mval = f2n + N;                      // N*MAXDEG
  int*   nbr  = (int*)(mval + (size_t)N * MAXDEG);  // N*MAXDEG
  int*   deg  = nbr + (size_t)N * MAXDEG;           // N
  float* z    = out + (size_t)N * N;          // output (tuple elem 1)
  float* A    = out;                          // output (tuple elem 0)

  hipLaunchKernelGGL(k_extract, dim3(N), dim3(256), 0, stream, adj, Mm, nbr, mval, deg);
  hipLaunchKernelGGL(k_gemm1, dim3((N / 32) * (HID / 64)), dim3(128), 0, stream, x, W1, h1);
  hipLaunchKernelGGL(k_f1, dim3(N / 4), dim3(256), 0, stream, h1, a1s, a1n, f1s, f1n);
  hipLaunchKernelGGL(k_attn1, dim3(N), dim3(256), 0, stream, h1, f1s, f1n, nbr, mval, deg, out1);
  hipLaunchKernelGGL(k_gemm2, dim3(N / 16), dim3(256), 0, stream, out1, W2, a2s, a2n, h2, f2s, f2n);
  hipLaunchKernelGGL(k_attn2, dim3(N / 4), dim3(256), 0, stream, h2, f2s, f2n, nbr, mval, deg, z);
  hipLaunchKernelGGL(k_apred, dim3(N / 1024, N / 8), dim3(256), 0, stream, z, A);
}

// Round 8
// 190.199 us; speedup vs baseline: 1.5826x; 1.0509x over previous
//
#include <hip/hip_runtime.h>
#include <math.h>

#define N 6144
#define ATTR 512
#define HID 256
#define EMB 16
#define ALPHA 0.2f
#define MAXDEG 192
#define BK 32

// ---------------------------------------------------------------------------
// K1: h1 = x @ W1  [6144,512]@[512,256] fp32.  (unchanged from round 7)
// Per-output accumulation is BIT-IDENTICAL to rounds 1/4/5/6/7 (sequential
// k = 0..511, single fmac chain).  DO NOT change the accumulation order:
// downstream sigmoid(s-1/s) has a 0/1 cliff at s=0 and any h1 perturbation
// flips near-zero dot products.
// ---------------------------------------------------------------------------
__global__ __launch_bounds__(128) void k_gemm1(const float* __restrict__ x,
                                               const float* __restrict__ W1,
                                               float* __restrict__ h1) {
  __shared__ float AsT[2][BK][36];   // [buf][k][row]
  __shared__ float Bs[2][BK][68];    // [buf][k][col]
  const int ct = blockIdx.x & 3;
  const int rt = blockIdx.x >> 2;
  const int tid = threadIdx.x;
  const int tx = tid & 15;
  const int ty = tid >> 4;
  const int row0 = rt * 32, col0 = ct * 64;
  const int ar0 = tid >> 3;
  const int akq = (tid & 7) * 4;
  const int bk0 = tid >> 4;
  const int bcq = (tid & 15) * 4;
  float4 pa0 = *(const float4*)&x[(size_t)(row0 + ar0) * ATTR + akq];
  float4 pa1 = *(const float4*)&x[(size_t)(row0 + ar0 + 16) * ATTR + akq];
  float4 pb0 = *(const float4*)&W1[(size_t)bk0 * HID + col0 + bcq];
  float4 pb1 = *(const float4*)&W1[(size_t)(bk0 + 8) * HID + col0 + bcq];
  float4 pb2 = *(const float4*)&W1[(size_t)(bk0 + 16) * HID + col0 + bcq];
  float4 pb3 = *(const float4*)&W1[(size_t)(bk0 + 24) * HID + col0 + bcq];
  float acc[4][4] = {};
  int buf = 0;
  for (int kt = 0; kt < ATTR; kt += BK) {
    AsT[buf][akq + 0][ar0] = pa0.x;
    AsT[buf][akq + 1][ar0] = pa0.y;
    AsT[buf][akq + 2][ar0] = pa0.z;
    AsT[buf][akq + 3][ar0] = pa0.w;
    AsT[buf][akq + 0][ar0 + 16] = pa1.x;
    AsT[buf][akq + 1][ar0 + 16] = pa1.y;
    AsT[buf][akq + 2][ar0 + 16] = pa1.z;
    AsT[buf][akq + 3][ar0 + 16] = pa1.w;
    *(float4*)&Bs[buf][bk0][bcq] = pb0;
    *(float4*)&Bs[buf][bk0 + 8][bcq] = pb1;
    *(float4*)&Bs[buf][bk0 + 16][bcq] = pb2;
    *(float4*)&Bs[buf][bk0 + 24][bcq] = pb3;
    __syncthreads();
    if (kt + BK < ATTR) {
      pa0 = *(const float4*)&x[(size_t)(row0 + ar0) * ATTR + kt + BK + akq];
      pa1 = *(const float4*)&x[(size_t)(row0 + ar0 + 16) * ATTR + kt + BK + akq];
      pb0 = *(const float4*)&W1[(size_t)(kt + BK + bk0) * HID + col0 + bcq];
      pb1 = *(const float4*)&W1[(size_t)(kt + BK + bk0 + 8) * HID + col0 + bcq];
      pb2 = *(const float4*)&W1[(size_t)(kt + BK + bk0 + 16) * HID + col0 + bcq];
      pb3 = *(const float4*)&W1[(size_t)(kt + BK + bk0 + 24) * HID + col0 + bcq];
    }
#pragma unroll 8
    for (int k = 0; k < BK; ++k) {
      const float4 a = *(const float4*)&AsT[buf][k][ty * 4];
      const float4 b = *(const float4*)&Bs[buf][k][tx * 4];
      acc[0][0] += a.x * b.x; acc[0][1] += a.x * b.y; acc[0][2] += a.x * b.z; acc[0][3] += a.x * b.w;
      acc[1][0] += a.y * b.x; acc[1][1] += a.y * b.y; acc[1][2] += a.y * b.z; acc[1][3] += a.y * b.w;
      acc[2][0] += a.z * b.x; acc[2][1] += a.z * b.y; acc[2][2] += a.z * b.z; acc[2][3] += a.z * b.w;
      acc[3][0] += a.w * b.x; acc[3][1] += a.w * b.y; acc[3][2] += a.w * b.z; acc[3][3] += a.w * b.w;
    }
    buf ^= 1;
  }
#pragma unroll
  for (int i = 0; i < 4; ++i) {
    float4 o = {acc[i][0], acc[i][1], acc[i][2], acc[i][3]};
    *(float4*)&h1[(size_t)(row0 + ty * 4 + i) * HID + col0 + tx * 4] = o;
  }
}

// ---------------------------------------------------------------------------
// K2: f1s[i] = h1[i,:]·a_self1 ; f1n[i] = h1[i,:]·a_neigh1   (one wave/row)
// ---------------------------------------------------------------------------
__global__ __launch_bounds__(256) void k_f1(const float* __restrict__ h1,
                                            const float* __restrict__ a_s,
                                            const float* __restrict__ a_n,
                                            float* __restrict__ f1s,
                                            float* __restrict__ f1n) {
  const int wid = (blockIdx.x * 256 + threadIdx.x) >> 6;
  const int lane = threadIdx.x & 63;
  const float* hrow = h1 + (size_t)wid * HID;
  float ss = 0.0f, sn = 0.0f;
#pragma unroll
  for (int c0 = 0; c0 < HID; c0 += 64) {
    float h = hrow[c0 + lane];
    ss += h * a_s[c0 + lane];
    sn += h * a_n[c0 + lane];
  }
#pragma unroll
  for (int off = 32; off; off >>= 1) {
    ss += __shfl_xor(ss, off);
    sn += __shfl_xor(sn, off);
  }
  if (lane == 0) { f1s[wid] = ss; f1n[wid] = sn; }
}

// ---------------------------------------------------------------------------
// K3a: adjacency scan — round-7 extract WITHOUT the M gather.  Pure coalesced
// adj stream + ballot compaction; scattered nbr stores are fire-and-forget
// (no load->store dependency).  nbr/deg bit-identical to rounds 4-7.
// ---------------------------------------------------------------------------
__global__ __launch_bounds__(256) void k_scan(const float* __restrict__ adj,
                                              int* __restrict__ nbr,
                                              int* __restrict__ deg) {
  __shared__ int wcnt[N / 1024][4];
  const int i = blockIdx.x;
  const int tid = threadIdx.x;
  const int w = tid >> 6, lane = tid & 63;
  const float4* arow = (const float4*)(adj + (size_t)i * N);
  int* nrow = nbr + (size_t)i * MAXDEG;
  float4 av[N / 1024];
#pragma unroll
  for (int r = 0; r < N / 1024; ++r) av[r] = arow[r * 256 + tid];
  unsigned long long m1[N / 1024], m2[N / 1024], m3[N / 1024], m4[N / 1024];
#pragma unroll
  for (int r = 0; r < N / 1024; ++r) {
    const float4 a = av[r];
    bool h0 = a.x > 0.f, h1b = a.y > 0.f, h2b = a.z > 0.f, h3b = a.w > 0.f;
    int cnt = (int)h0 + (int)h1b + (int)h2b + (int)h3b;
    m1[r] = __ballot(cnt >= 1);
    m2[r] = __ballot(cnt >= 2);
    m3[r] = __ballot(cnt >= 3);
    m4[r] = __ballot(cnt >= 4);
    if (lane == 0) {
      wcnt[r][w] = __popcll(m1[r]) + __popcll(m2[r]) + __popcll(m3[r]) + __popcll(m4[r]);
    }
  }
  __syncthreads();
  const unsigned long long lt = (1ull << lane) - 1ull;
  int count = 0;
#pragma unroll
  for (int r = 0; r < N / 1024; ++r) {
    const float4 a = av[r];
    bool h0 = a.x > 0.f, h1b = a.y > 0.f, h2b = a.z > 0.f, h3b = a.w > 0.f;
    int woff = 0;
#pragma unroll
    for (int q = 0; q < 4; ++q) woff += (q < w) ? wcnt[r][q] : 0;
    int pos = count + woff + __popcll(m1[r] & lt) + __popcll(m2[r] & lt) +
              __popcll(m3[r] & lt) + __popcll(m4[r] & lt);
    const int idx = r * 1024 + tid * 4;
    if (h0) { if (pos < MAXDEG) nrow[pos] = idx;     ++pos; }
    if (h1b){ if (pos < MAXDEG) nrow[pos] = idx + 1; ++pos; }
    if (h2b){ if (pos < MAXDEG) nrow[pos] = idx + 2; ++pos; }
    if (h3b){ if (pos < MAXDEG) nrow[pos] = idx + 3; ++pos; }
    count += wcnt[r][0] + wcnt[r][1] + wcnt[r][2] + wcnt[r][3];
  }
  if (tid == 0) deg[i] = count > MAXDEG ? MAXDEG : count;
}

// ---------------------------------------------------------------------------
// K3b: lane-parallel M gather: mval[i][s] = M[i*N + nbr[i][s]] for s < deg[i].
// One wave per row: 64 scattered loads per instruction, all independent
// (vs the old branch-serialized load->store chain).  Values identical.
// ---------------------------------------------------------------------------
__global__ __launch_bounds__(256) void k_gather(const float* __restrict__ Mm,
                                                const int* __restrict__ nbr,
                                                const int* __restrict__ deg,
                                                float* __restrict__ mval) {
  const int i = (blockIdx.x * 256 + threadIdx.x) >> 6;
  const int lane = threadIdx.x & 63;
  const int d = deg[i];
  const int* nrow = nbr + (size_t)i * MAXDEG;
  const float* mrow = Mm + (size_t)i * N;
  float* mout = mval + (size_t)i * MAXDEG;
#pragma unroll
  for (int s0 = 0; s0 < MAXDEG; s0 += 64) {
    const int s = s0 + lane;
    if (s < d) mout[s] = mrow[nrow[s]];
  }
}

// ---------------------------------------------------------------------------
// K4: sparse attention layer 1: out1[i,:] = elu( sum_j attn_ij * h1[j,:] )
// ---------------------------------------------------------------------------
__global__ __launch_bounds__(256) void k_attn1(const float* __restrict__ h1,
                                               const float* __restrict__ f1s,
                                               const float* __restrict__ f1n,
                                               const int* __restrict__ nbr,
                                               const float* __restrict__ mval,
                                               const int* __restrict__ deg,
                                               float* __restrict__ out1) {
  __shared__ float p[MAXDEG];
  __shared__ int nb[MAXDEG];
  const int i = blockIdx.x;
  const int tid = threadIdx.x;
  const int d = deg[i];
  if (d > 0 && tid < 64) {
    const float fsi = f1s[i];
    float lmax = -3.0e38f;
    for (int j = tid; j < d; j += 64) {
      int nj = nbr[(size_t)i * MAXDEG + j];
      nb[j] = nj;
      float v = (fsi + f1n[nj]) * mval[(size_t)i * MAXDEG + j];
      float e = v > 0.0f ? v : ALPHA * v;
      p[j] = e;
      lmax = fmaxf(lmax, e);
    }
#pragma unroll
    for (int off = 32; off; off >>= 1) lmax = fmaxf(lmax, __shfl_xor(lmax, off));
    float lsum = 0.0f;
    for (int j = tid; j < d; j += 64) {
      float t = expf(p[j] - lmax);
      p[j] = t;
      lsum += t;
    }
#pragma unroll
    for (int off = 32; off; off >>= 1) lsum += __shfl_xor(lsum, off);
    float inv = 1.0f / lsum;
    for (int j = tid; j < d; j += 64) p[j] *= inv;
  }
  __syncthreads();
  float acc = 0.0f;
  if (d > 0) {
    for (int j = 0; j < d; ++j) {
      acc += p[j] * h1[(size_t)nb[j] * HID + tid];
    }
  } else {
    for (int j = 0; j < N; ++j) acc += h1[(size_t)j * HID + tid];
    acc *= (1.0f / (float)N);
  }
  out1[(size_t)i * HID + tid] = acc > 0.0f ? acc : expm1f(acc);
}

// ---------------------------------------------------------------------------
// K5: h2 = out1 @ W2 ([6144,256]@[256,16]) + f2s/f2n epilogue
// ---------------------------------------------------------------------------
__global__ __launch_bounds__(256) void k_gemm2(const float* __restrict__ out1,
                                               const float* __restrict__ W2,
                                               const float* __restrict__ a_s,
                                               const float* __restrict__ a_n,
                                               float* __restrict__ h2,
                                               float* __restrict__ f2s,
                                               float* __restrict__ f2n) {
  __shared__ float Hs[16][HID + 1];
  __shared__ float Ws[HID][EMB + 1];
  const int row0 = blockIdx.x * 16;
  const int tid = threadIdx.x;
  for (int l = tid; l < 16 * HID; l += 256) {
    Hs[l >> 8][l & 255] = out1[(size_t)(row0 + (l >> 8)) * HID + (l & 255)];
  }
  for (int l = tid; l < HID * EMB; l += 256) {
    Ws[l >> 4][l & 15] = W2[l];
  }
  __syncthreads();
  const int r = tid >> 4, c = tid & 15;
  float acc = 0.0f;
  for (int k = 0; k < HID; ++k) acc += Hs[r][k] * Ws[k][c];
  h2[(size_t)(row0 + r) * EMB + c] = acc;
  float vs = acc * a_s[c], vn = acc * a_n[c];
#pragma unroll
  for (int off = 1; off < 16; off <<= 1) {
    vs += __shfl_xor(vs, off);
    vn += __shfl_xor(vn, off);
  }
  if (c == 0) { f2s[row0 + r] = vs; f2n[row0 + r] = vn; }
}

// ---------------------------------------------------------------------------
// K6: sparse attention layer 2 + elu + L2-normalize -> z  (one wave per row)
// ---------------------------------------------------------------------------
__global__ __launch_bounds__(256) void k_attn2(const float* __restrict__ h2,
                                               const float* __restrict__ f2s,
                                               const float* __restrict__ f2n,
                                               const int* __restrict__ nbr,
                                               const float* __restrict__ mval,
                                               const int* __restrict__ deg,
                                               float* __restrict__ z) {
  __shared__ float p[4][MAXDEG];
  __shared__ int nb[4][MAXDEG];
  const int w = threadIdx.x >> 6, lane = threadIdx.x & 63;
  const int i = blockIdx.x * 4 + w;
  const int d = deg[i];
  if (d > 0) {
    const float fsi = f2s[i];
    float lmax = -3.0e38f;
    for (int j = lane; j < d; j += 64) {
      int nj = nbr[(size_t)i * MAXDEG + j];
      nb[w][j] = nj;
      float v = (fsi + f2n[nj]) * mval[(size_t)i * MAXDEG + j];
      float e = v > 0.0f ? v : ALPHA * v;
      p[w][j] = e;
      lmax = fmaxf(lmax, e);
    }
#pragma unroll
    for (int off = 32; off; off >>= 1) lmax = fmaxf(lmax, __shfl_xor(lmax, off));
    float lsum = 0.0f;
    for (int j = lane; j < d; j += 64) {
      float t = expf(p[w][j] - lmax);
      p[w][j] = t;
      lsum += t;
    }
#pragma unroll
    for (int off = 32; off; off >>= 1) lsum += __shfl_xor(lsum, off);
    float inv = 1.0f / lsum;
    for (int j = lane; j < d; j += 64) p[w][j] *= inv;
  }
  __syncthreads();
  const int g = lane >> 4, c = lane & 15;
  float acc = 0.0f;
  if (d > 0) {
    for (int j = g; j < d; j += 4) {
      acc += p[w][j] * h2[(size_t)nb[w][j] * EMB + c];
    }
  } else {
    for (int j = g; j < N; j += 4) acc += h2[(size_t)j * EMB + c];
  }
  acc += __shfl_xor(acc, 16);
  acc += __shfl_xor(acc, 32);
  if (d == 0) acc *= (1.0f / (float)N);
  float val = acc > 0.0f ? acc : expm1f(acc);
  float sq = val * val;
#pragma unroll
  for (int off = 1; off < 16; off <<= 1) sq += __shfl_xor(sq, off);
  float nrm = fmaxf(sqrtf(sq), 1e-12f);
  float zv = val / nrm;
  if (lane < 16) z[(size_t)i * EMB + lane] = zv;
}

// ---------------------------------------------------------------------------
// K7: A[i,j] = sigmoid(s - 1/s), s = z_i · z_j.  8 rows x 1024 cols per block
// ---------------------------------------------------------------------------
__device__ __forceinline__ float sig_of(float s) {
  float t = s - 1.0f / s;
  return 1.0f / (1.0f + expf(-t));
}

__global__ __launch_bounds__(256) void k_apred(const float* __restrict__ z,
                                               float* __restrict__ A) {
  __shared__ float zi_s[8 * EMB];
  const int i0 = blockIdx.y * 8;
  const int tid = threadIdx.x;
  if (tid < 8 * EMB) zi_s[tid] = z[(size_t)i0 * EMB + tid];
  const int j0 = blockIdx.x * 1024 + tid * 4;
  float zj[4][EMB];
  const float4* zp = (const float4*)(z + (size_t)j0 * EMB);
#pragma unroll
  for (int q = 0; q < 4; ++q) {
#pragma unroll
    for (int kk = 0; kk < 4; ++kk) {
      float4 v = zp[q * 4 + kk];
      zj[q][kk * 4 + 0] = v.x;
      zj[q][kk * 4 + 1] = v.y;
      zj[q][kk * 4 + 2] = v.z;
      zj[q][kk * 4 + 3] = v.w;
    }
  }
  __syncthreads();
  for (int ii = 0; ii < 8; ++ii) {
    float acc0 = 0.0f, acc1 = 0.0f, acc2 = 0.0f, acc3 = 0.0f;
#pragma unroll
    for (int k = 0; k < EMB; ++k) {
      float a = zi_s[ii * EMB + k];
      acc0 += a * zj[0][k];
      acc1 += a * zj[1][k];
      acc2 += a * zj[2][k];
      acc3 += a * zj[3][k];
    }
    float4 o;
    o.x = sig_of(acc0);
    o.y = sig_of(acc1);
    o.z = sig_of(acc2);
    o.w = sig_of(acc3);
    *(float4*)(A + (size_t)(i0 + ii) * N + j0) = o;
  }
}

// ---------------------------------------------------------------------------
extern "C" void kernel_launch(void* const* d_in, const int* in_sizes, int n_in,
                              void* d_out, int out_size, void* d_ws, size_t ws_size,
                              hipStream_t stream) {
  const float* x   = (const float*)d_in[0];
  const float* adj = (const float*)d_in[1];
  const float* Mm  = (const float*)d_in[2];
  const float* W1  = (const float*)d_in[3];
  const float* a1s = (const float*)d_in[4];
  const float* a1n = (const float*)d_in[5];
  const float* W2  = (const float*)d_in[6];
  const float* a2s = (const float*)d_in[7];
  const float* a2n = (const float*)d_in[8];

  // Scratch carved from the A_pred region of d_out (fully overwritten by
  // k_apred, which reads only z). Round-1 layout, unchanged.
  float* out = (float*)d_out;
  float* h1   = out;                          // N*HID
  float* out1 = h1 + (size_t)N * HID;         // N*HID
  float* h2   = out1 + (size_t)N * HID;       // N*EMB
  float* f1s  = h2 + (size_t)N * EMB;         // N
  float* f1n  = f1s + N;                      // N
  float* f2s  = f1n + N;                      // N
  float* f2n  = f2s + N;                      // N
  float* mval = f2n + N;                      // N*MAXDEG
  int*   nbr  = (int*)(mval + (size_t)N * MAXDEG);  // N*MAXDEG
  int*   deg  = nbr + (size_t)N * MAXDEG;           // N
  float* z    = out + (size_t)N * N;          // output (tuple elem 1)
  float* A    = out;                          // output (tuple elem 0)

  hipLaunchKernelGGL(k_scan, dim3(N), dim3(256), 0, stream, adj, nbr, deg);
  hipLaunchKernelGGL(k_gather, dim3(N / 4), dim3(256), 0, stream, Mm, nbr, deg, mval);
  hipLaunchKernelGGL(k_gemm1, dim3((N / 32) * (HID / 64)), dim3(128), 0, stream, x, W1, h1);
  hipLaunchKernelGGL(k_f1, dim3(N / 4), dim3(256), 0, stream, h1, a1s, a1n, f1s, f1n);
  hipLaunchKernelGGL(k_attn1, dim3(N), dim3(256), 0, stream, h1, f1s, f1n, nbr, mval, deg, out1);
  hipLaunchKernelGGL(k_gemm2, dim3(N / 16), dim3(256), 0, stream, out1, W2, a2s, a2n, h2, f2s, f2n);
  hipLaunchKernelGGL(k_attn2, dim3(N / 4), dim3(256), 0, stream, h2, f2s, f2n, nbr, mval, deg, z);
  hipLaunchKernelGGL(k_apred, dim3(N / 1024, N / 8), dim3(256), 0, stream, z, A);
}